// Round 11
// baseline (629.834 us; speedup 1.0000x reference)
//
#include <hip/hip_runtime.h>
#include <hip/hip_bf16.h>

#define DM   1024
#define DFF  4096
#define NB   4
#define SS   2048
#define NH   16
#define DK   64
#define MROWS (NB*SS)   // 8192

typedef __attribute__((ext_vector_type(8))) short bfx8;
typedef __attribute__((ext_vector_type(4))) float fx4;
typedef unsigned int u32;
typedef unsigned short u16;
typedef unsigned long long u64;

static __device__ __forceinline__ u16 f2bf(float f) {
  union { __hip_bfloat16 h; u16 u; } cv;
  cv.h = __float2bfloat16(f);
  return cv.u;
}
static __device__ __forceinline__ u32 pk2bf(float a, float b) {
  return (u32)f2bf(a) | ((u32)f2bf(b) << 16);
}

static __device__ __forceinline__ void async16(void* lds, const void* g) {
  typedef const __attribute__((address_space(1))) unsigned int* gp_t;
  typedef __attribute__((address_space(3))) unsigned int* lp_t;
  __builtin_amdgcn_global_load_lds((gp_t)g, (lp_t)lds, 16, 0, 0);
}

// ------------- ALL weight transposes in one launch: out[n][k] = in[k][n] ----
// blocks 0..4095: wq/wk/wv/wo (1024x1024); 4096..8191: w1 (1024x4096);
// 8192..12287: w2 (4096x1024)
__global__ __launch_bounds__(256) void k_transpose_all(
    const float* __restrict__ wq, const float* __restrict__ wk,
    const float* __restrict__ wv, const float* __restrict__ wo,
    const float* __restrict__ w1, const float* __restrict__ w2,
    u16* __restrict__ wqkv, u16* __restrict__ wot,
    u16* __restrict__ w1t,  u16* __restrict__ w2t) {
  __shared__ float t[32][33];
  const int idx = blockIdx.x;
  const float* in; u16* out; int K, N, bx, by;
  if (idx < 4096) {
    const int m = idx >> 10, tl = idx & 1023;
    in  = (m == 0) ? wq : (m == 1) ? wk : (m == 2) ? wv : wo;
    out = (m < 3) ? (wqkv + (size_t)m * 1024 * 1024) : wot;
    K = 1024; N = 1024; bx = tl & 31; by = tl >> 5;
  } else if (idx < 8192) {
    const int tl = idx - 4096;
    in = w1; out = w1t; K = 1024; N = 4096; bx = tl & 127; by = tl >> 7;
  } else {
    const int tl = idx - 8192;
    in = w2; out = w2t; K = 4096; N = 1024; bx = tl & 31; by = tl >> 5;
  }
  const int n0 = bx * 32, k0 = by * 32;
  const int tx = threadIdx.x & 31, ty = threadIdx.x >> 5;  // 32 x 8
#pragma unroll
  for (int j = 0; j < 4; j++)
    t[ty + j * 8][tx] = in[(size_t)(k0 + ty + j * 8) * N + n0 + tx];
  __syncthreads();
#pragma unroll
  for (int j = 0; j < 4; j++)
    out[(size_t)(n0 + ty + j * 8) * K + k0 + tx] = f2bf(t[tx][ty + j * 8]);
}

// ---------------- layernorm: f32 in -> bf16 out, one wave per row ----------
__global__ __launch_bounds__(256) void k_layernorm(const float* __restrict__ x,
                                                   const float* __restrict__ g,
                                                   const float* __restrict__ b,
                                                   u16* __restrict__ out) {
  const int row  = blockIdx.x * 4 + (threadIdx.x >> 6);
  const int lane = threadIdx.x & 63;
  const float* xr = x + (size_t)row * DM;
  float4 vb[4];
  float s = 0.f, s2 = 0.f;
#pragma unroll
  for (int j = 0; j < 4; j++) {
    float4 v = *(const float4*)(xr + j * 256 + lane * 4);
    vb[j] = v;
    s  += v.x + v.y + v.z + v.w;
    s2 += v.x * v.x + v.y * v.y + v.z * v.z + v.w * v.w;
  }
#pragma unroll
  for (int off = 1; off < 64; off <<= 1) {
    s  += __shfl_xor(s,  off);
    s2 += __shfl_xor(s2, off);
  }
  const float mu   = s * (1.f / DM);
  const float var  = s2 * (1.f / DM) - mu * mu;
  const float rstd = rsqrtf(var + 1e-5f);
  u16* orow = out + (size_t)row * DM;
#pragma unroll
  for (int j = 0; j < 4; j++) {
    const int col = j * 256 + lane * 4;
    uint2 o;
    o.x = pk2bf((vb[j].x - mu) * rstd * g[col + 0] + b[col + 0],
                (vb[j].y - mu) * rstd * g[col + 1] + b[col + 1]);
    o.y = pk2bf((vb[j].z - mu) * rstd * g[col + 2] + b[col + 2],
                (vb[j].w - mu) * rstd * g[col + 3] + b[col + 3]);
    *(uint2*)(orow + col) = o;
  }
}

// ---------------- GEMM: C[M,N] = A[M,K](bf16) @ BT[N,K](bf16)^T + bias -----
// BM=256, BN=128, 8 waves (4M x 2N), wave tile 64x64, BK=32.
// A: global_load_lds into RING-4 LDS (64 KB), XOR swizzle (proven r8).
// B: DIRECT global->register via inline-asm dwordx4 (double-buffered bA/bB,
//    unroll-by-2) -- no B LDS traffic, full-sector reads (quarter-wave = one
//    row's 64B). ONE barrier per K-tile; counted vmcnt: steady vmcnt(2)
//    retires A(t+1)+B(t+1), leaves A(t+3). sched_barrier(0) after each wait
//    (rule #18: keeps MFMA from hoisting past the vmcnt for its B-regs).
// EPI: 1 = f32 out (+res), 2 = bf16 gelu out, 4 = fused QKV
template <int EPI>
__global__ __launch_bounds__(512) void k_gemm_bt(const u16* __restrict__ A,
                                                 const u16* __restrict__ BT,
                                                 const float* __restrict__ bias0,
                                                 const float* __restrict__ bias1,
                                                 const float* __restrict__ bias2,
                                                 const float* __restrict__ res,
                                                 void* __restrict__ outp,
                                                 int M, int N, int K) {
  constexpr int ABUF = 256 * 32 * 2;         // 16 KB per K-tile buffer
  __shared__ char Al[4 * ABUF];              // 64 KB (reused as epilogue bounce)

  const int tid = threadIdx.x, wave = tid >> 6, lane = tid & 63;
  // XCD-aware chunked swizzle (nwg % 8 == 0 for all our launches)
  const int nwg = gridDim.x * gridDim.y;
  const int bid = blockIdx.y * gridDim.x + blockIdx.x;
  const int swz = (bid & 7) * (nwg >> 3) + (bid >> 3);
  const int m0 = (swz / gridDim.x) * 256, n0 = (swz % gridDim.x) * 128;
  const int wr = wave >> 1, wc = wave & 1;
  const int wm = wr * 64, wn = wc * 64;
  const int la = lane & 15, lg = lane >> 4;
  const int psw = (la >> 1) & 3;             // read-side XOR swizzle

  fx4 acc[4][4];
#pragma unroll
  for (int i = 0; i < 4; i++)
#pragma unroll
    for (int j = 0; j < 4; j++) acc[i][j] = fx4{0.f, 0.f, 0.f, 0.f};

  // A staging: thread tid -> LDS phys (row=tid>>2, slot=tid&3) per 8KB chunk;
  // fetch logical slot = (tid&3) ^ ((tid>>3)&3)  (inverse of read swizzle)
  const int arow = tid >> 2;
  const int aslot = ((tid & 3) ^ ((tid >> 3) & 3)) * 8;
  const u16* gA = A + (size_t)(m0 + arow) * K + aslot;

  auto stageA = [&](int buf, int kt) {
#pragma unroll
    for (int j = 0; j < 2; j++)
      async16(Al + buf * ABUF + j * 8192 + wave * 1024, gA + (size_t)(j * 128) * K + kt);
  };

  // B lane bases (byte addresses). Quarter-wave {la,la+16,la+32,la+48} covers
  // one BT row's 64 contiguous bytes -> full-sector global reads.
  u64 bb[4];
#pragma unroll
  for (int nt = 0; nt < 4; nt++)
    bb[nt] = (u64)(BT + (size_t)(n0 + wn + nt * 16 + la) * K + lg * 8);

  auto loadB = [&](bfx8 (&dst)[4], int kt) {
#pragma unroll
    for (int nt = 0; nt < 4; nt++) {
      u64 a = bb[nt] + (u64)kt * 2;
      asm volatile("global_load_dwordx4 %0, %1, off"
                   : "=v"(dst[nt]) : "v"(a) : "memory");
    }
  };

  const int nk = K >> 5;
  bfx8 bA[4], bB[4];
  loadB(bA, 0);                 // B(0): 4 loads
  stageA(0, 0);                 // A(0): 2
  stageA(1, 32);                // A(1): 2
  stageA(2, 64);                // A(2): 2
  asm volatile("s_waitcnt vmcnt(4)" ::: "memory");   // retire B(0)+A(0)
  __builtin_amdgcn_sched_barrier(0);
  __builtin_amdgcn_s_barrier();
  asm volatile("" ::: "memory");

  auto tile = [&](int t, bfx8 (&bcur)[4], bfx8 (&bnext)[4]) {
    const char* Ab = (const char*)Al + (t & 3) * ABUF;
    bfx8 av[4];
#pragma unroll
    for (int i = 0; i < 4; i++)
      av[i] = *(const bfx8*)(Ab + (wm + i * 16 + la) * 64 + (lg ^ psw) * 16);
    if (t + 1 < nk) loadB(bnext, (t + 1) * 32);
    if (t + 3 < nk) stageA((t + 3) & 3, (t + 3) * 32);
    __builtin_amdgcn_s_setprio(1);
#pragma unroll
    for (int mt = 0; mt < 4; mt++)
#pragma unroll
      for (int nt = 0; nt < 4; nt++)
        acc[mt][nt] = __builtin_amdgcn_mfma_f32_16x16x32_bf16(av[mt], bcur[nt], acc[mt][nt], 0, 0, 0);
    __builtin_amdgcn_s_setprio(0);
    const int rem = nk - 1 - t;
    if (rem >= 3)      { asm volatile("s_waitcnt vmcnt(2)" ::: "memory"); }
    else if (rem >= 1) { asm volatile("s_waitcnt vmcnt(0)" ::: "memory"); }
    __builtin_amdgcn_sched_barrier(0);
    __builtin_amdgcn_s_barrier();
    asm volatile("" ::: "memory");
  };

  for (int t = 0; t < nk; t += 2) {
    tile(t,     bA, bB);
    tile(t + 1, bB, bA);
  }

  // ============ epilogue ============
  // Per-wave LDS bounce scratch (K-loop LDS dead). 16 rows x 64 cols f32,
  // row stride 68 (bank-clean). 4352 B/wave x 8 = 34 KB <= 64 KB.
  float* scr = (float*)(Al) + (size_t)wave * (68 * 16);

  auto emit_bf16 = [&](u16* base, size_t ld, int mrow0, int ncol0,
                       const float v[4][4] /*[nt][vv]*/) {
#pragma unroll
    for (int nt = 0; nt < 4; nt++)
#pragma unroll
      for (int vv = 0; vv < 4; vv++)
        scr[(lg * 4 + vv) * 68 + nt * 16 + la] = v[nt][vv];
    asm volatile("s_waitcnt lgkmcnt(0)" ::: "memory");
#pragma unroll
    for (int p = 0; p < 4; p++) {
      const int r  = p * 4 + (lane >> 4);
      const int cg = lane & 15;
      float4 q = *(const float4*)&scr[r * 68 + cg * 4];
      uint2 o;
      o.x = pk2bf(q.x, q.y);
      o.y = pk2bf(q.z, q.w);
      *(uint2*)(base + (size_t)(mrow0 + r) * ld + ncol0 + cg * 4) = o;
    }
    asm volatile("s_waitcnt lgkmcnt(0)" ::: "memory");
  };

  if constexpr (EPI == 4) {
    const int reg = n0 >> 10;  // 0=Q, 1=K, 2=V (block-uniform)
    const float* bp = (reg == 0) ? bias0 : (reg == 1) ? bias1 : bias2;
    if (reg < 2) {
      u16* base = (u16*)outp + (size_t)reg * (8u * 1024 * 1024);
#pragma unroll
      for (int mt = 0; mt < 4; mt++) {
        float v[4][4];
#pragma unroll
        for (int nt = 0; nt < 4; nt++) {
          const float bs = bp[(n0 + wn + nt * 16 + la) & 1023];
#pragma unroll
          for (int vv = 0; vv < 4; vv++) v[nt][vv] = acc[mt][nt][vv] + bs;
        }
        emit_bf16(base, 1024, m0 + wm + mt * 16, (n0 + wn) & 1023, v);
      }
    } else {
#pragma unroll
      for (int nt = 0; nt < 4; nt++) {
        const int nl = (n0 + wn + nt * 16 + la) & 1023;
        const float bs = bp[nl];
        const int hh = nl >> 6, d = nl & 63;
#pragma unroll
        for (int mt = 0; mt < 4; mt++) {
          const int m = m0 + wm + mt * 16 + lg * 4;
          const int bb2 = m >> 11, s = m & 2047;
          u16* vp = (u16*)outp + 16u * 1024 * 1024 +
                    (((size_t)bb2 * NH + hh) * DK + d) * SS + s;
          uint2 o;
          o.x = pk2bf(acc[mt][nt][0] + bs, acc[mt][nt][1] + bs);
          o.y = pk2bf(acc[mt][nt][2] + bs, acc[mt][nt][3] + bs);
          *(uint2*)vp = o;
        }
      }
    }
  } else if constexpr (EPI == 2) {
#pragma unroll
    for (int mt = 0; mt < 4; mt++) {
      float v[4][4];
#pragma unroll
      for (int nt = 0; nt < 4; nt++) {
        const float bs = bias0[n0 + wn + nt * 16 + la];
#pragma unroll
        for (int vv = 0; vv < 4; vv++) {
          const float val = acc[mt][nt][vv] + bs;
          v[nt][vv] = 0.5f * val * (1.f + erff(val * 0.70710678118f));
        }
      }
      emit_bf16((u16*)outp, N, m0 + wm + mt * 16, n0 + wn, v);
    }
  } else {
#pragma unroll
    for (int nt = 0; nt < 4; nt++) {
      const int n = n0 + wn + nt * 16 + la;
      const float bs = bias0[n];
#pragma unroll
      for (int mt = 0; mt < 4; mt++) {
#pragma unroll
        for (int vv = 0; vv < 4; vv++) {
          const int m = m0 + wm + mt * 16 + lg * 4 + vv;
          const size_t idx = (size_t)m * N + n;
          ((float*)outp)[idx] = res[idx] + acc[mt][nt][vv] + bs;
        }
      }
    }
  }
}

// ---------------- causal flash attention, swapped-QK^T, split-KV ----------
// grid 1024 x 512 threads = 8 waves = 2 groups of 4. Per block: 128 q-rows.
// Group g processes KV chunks (2i+g)*64; each group has its own double-buffered
// K/V in LDS (64 KB total). End: merge the two online-softmax partials via LDS.
__global__ __launch_bounds__(512, 4) void k_attn(const u16* __restrict__ q,
                                                 const u16* __restrict__ k,
                                                 const u16* __restrict__ vt,
                                                 u16* __restrict__ att) {
  __shared__ char sm[65536];   // [group][ K 2x8KB | V 2x8KB ]; merge scratch aliases
  const int bid = blockIdx.x;
  const int bq = 15 - (bid >> 6);
  const int bh = bid & 63;
  const int b = bh >> 4, h = bh & 15;

  const int tid = threadIdx.x, wave = tid >> 6, lane = tid & 63;
  const int g = wave >> 2, wv4 = wave & 3;
  const int la = lane & 15, lg = lane >> 4;
  const int q0 = bq * 128;

  // Q fragments (B-operand): lane holds Q[q=qt*16+la][d = f*32 + lg*8 + j]
  bfx8 qf[2][2];
#pragma unroll
  for (int qt = 0; qt < 2; qt++) {
    const u16* qp = q + (size_t)(b * SS + q0 + wv4 * 32 + qt * 16 + la) * DM + h * DK + lg * 8;
#pragma unroll
    for (int f = 0; f < 2; f++) qf[qt][f] = *(const bfx8*)(qp + f * 32);
  }

  fx4 acc[2][4];
#pragma unroll
  for (int qt = 0; qt < 2; qt++)
#pragma unroll
    for (int dt = 0; dt < 4; dt++) acc[qt][dt] = fx4{0.f, 0.f, 0.f, 0.f};
  float mold[2] = {-10000.f, -10000.f};   // finite floor (log2 units)
  float lsum[2] = {0.f, 0.f};             // per-lane partial

  // staging (pre-swizzled global source, linear LDS dest)
  const int srow = lane >> 3;                   // 0..7
  const int sslot = (lane & 7) ^ srow;          // 16B slot
  const u16* kg0 = k  + (size_t)(b * SS + wv4 * 16 + srow) * DM + h * DK + sslot * 8;
  const u16* vg0 = vt + (size_t)((b * NH + h) * DK + wv4 * 16 + srow) * SS + sslot * 8;
  char* kbase = sm + g * 32768 + wv4 * 2048;            // + buf*8192
  char* vbase = sm + g * 32768 + 16384 + wv4 * 2048;

  const float c1 = 0.18033688f;  // 0.125 * log2(e)
  const int niter = bq + 1;      // chunks for this group: c = 2*i + g

  auto stage = [&](int buf, int i) {
    const int c0 = (2 * i + g) * 64;
#pragma unroll
    for (int j = 0; j < 2; j++)
      async16(kbase + buf * 8192 + j * 1024, kg0 + (size_t)(c0 + j * 8) * DM);
#pragma unroll
    for (int j = 0; j < 2; j++)
      async16(vbase + buf * 8192 + j * 1024, vg0 + (size_t)(j * 8) * SS + c0);
  };

  stage(0, 0);
  int cur = 0;
  const int sw = la & 7;

  for (int i = 0; i < niter; i++) {
    __syncthreads();                 // buf[cur] staged; prev reads done
    if (i + 1 < niter) stage(cur ^ 1, i + 1);
    const int c0 = (2 * i + g) * 64;
    const bool msk = (i == niter - 1);
    const char* Kb = sm + g * 32768 + cur * 8192;
    const char* Vb = sm + g * 32768 + 16384 + cur * 8192;

    // ---- S^T = K @ Q^T : lane holds S^T[kv=t*16+lg*4+r][q=qt*16+la] ----
    fx4 st[2][4];
    __builtin_amdgcn_s_setprio(1);
#pragma unroll
    for (int t = 0; t < 4; t++) {
      const char* kr = Kb + (size_t)(t * 16 + la) * 128;
      bfx8 kf0 = *(const bfx8*)(kr + ((0 + lg) ^ sw) * 16);
      bfx8 kf1 = *(const bfx8*)(kr + ((4 + lg) ^ sw) * 16);
#pragma unroll
      for (int qt = 0; qt < 2; qt++) {
        fx4 z = fx4{0.f, 0.f, 0.f, 0.f};
        z = __builtin_amdgcn_mfma_f32_16x16x32_bf16(kf0, qf[qt][0], z, 0, 0, 0);
        z = __builtin_amdgcn_mfma_f32_16x16x32_bf16(kf1, qf[qt][1], z, 0, 0, 0);
        st[qt][t] = z;
      }
    }
    __builtin_amdgcn_s_setprio(0);

    if (msk) {
#pragma unroll
      for (int qt = 0; qt < 2; qt++) {
        const int qir = q0 + wv4 * 32 + qt * 16 + la;
#pragma unroll
        for (int t = 0; t < 4; t++)
#pragma unroll
          for (int r = 0; r < 4; r++)
            if (c0 + t * 16 + lg * 4 + r > qir) st[qt][t][r] = -1e9f;
      }
    }

    // ---- softmax: shuffle-free deferred path; per-lane partial lsum ----
    float lmx[2];
#pragma unroll
    for (int qt = 0; qt < 2; qt++) {
      float mx = fmaxf(fmaxf(st[qt][0][0], st[qt][0][1]), fmaxf(st[qt][0][2], st[qt][0][3]));
#pragma unroll
      for (int t = 1; t < 4; t++)
        mx = fmaxf(mx, fmaxf(fmaxf(st[qt][t][0], st[qt][t][1]), fmaxf(st[qt][t][2], st[qt][t][3])));
      lmx[qt] = mx * c1;
    }
    const bool def = (lmx[0] <= mold[0] + 8.f) && (lmx[1] <= mold[1] + 8.f);
    if (!__all(def)) {
#pragma unroll
      for (int qt = 0; qt < 2; qt++) {
        float mx = lmx[qt];
        mx = fmaxf(mx, __shfl_xor(mx, 16));
        mx = fmaxf(mx, __shfl_xor(mx, 32));
        const float mnew  = fmaxf(mold[qt], mx);
        const float scale = exp2f(mold[qt] - mnew);
        mold[qt] = mnew;
        lsum[qt] *= scale;
#pragma unroll
        for (int dt = 0; dt < 4; dt++) {
          acc[qt][dt][0] *= scale; acc[qt][dt][1] *= scale;
          acc[qt][dt][2] *= scale; acc[qt][dt][3] *= scale;
        }
      }
    }
    u32 W[2][4][2];
#pragma unroll
    for (int qt = 0; qt < 2; qt++) {
      float ps = 0.f;
#pragma unroll
      for (int t = 0; t < 4; t++) {
        float p0 = exp2f(fmaf(st[qt][t][0], c1, -mold[qt]));
        float p1 = exp2f(fmaf(st[qt][t][1], c1, -mold[qt]));
        float p2 = exp2f(fmaf(st[qt][t][2], c1, -mold[qt]));
        float p3 = exp2f(fmaf(st[qt][t][3], c1, -mold[qt]));
        ps += (p0 + p1) + (p2 + p3);
        W[qt][t][0] = pk2bf(p0, p1);
        W[qt][t][1] = pk2bf(p2, p3);
      }
      lsum[qt] += ps;
    }

    // ---- PV: O^T += V^T @ P^T (P B-frag rebuilt in-register via shfl) ----
    const int sLo = la + ((lg & 1) << 5);
    const int sHi = sLo + 16;
    const bool tHi = (lg >> 1) & 1;
#pragma unroll
    for (int f = 0; f < 2; f++) {
      bfx8 pf[2];
#pragma unroll
      for (int qt = 0; qt < 2; qt++) {
        const u32 a0 = __shfl(W[qt][2 * f][0], sLo), b0 = __shfl(W[qt][2 * f + 1][0], sLo);
        const u32 a1 = __shfl(W[qt][2 * f][1], sLo), b1 = __shfl(W[qt][2 * f + 1][1], sLo);
        const u32 a2 = __shfl(W[qt][2 * f][0], sHi), b2 = __shfl(W[qt][2 * f + 1][0], sHi);
        const u32 a3 = __shfl(W[qt][2 * f][1], sHi), b3 = __shfl(W[qt][2 * f + 1][1], sHi);
        union { u32 u[4]; bfx8 v; } pu;
        pu.u[0] = tHi ? b0 : a0;
        pu.u[1] = tHi ? b1 : a1;
        pu.u[2] = tHi ? b2 : a2;
        pu.u[3] = tHi ? b3 : a3;
        pf[qt] = pu.v;
      }
      __builtin_amdgcn_s_setprio(1);
#pragma unroll
      for (int dt = 0; dt < 4; dt++) {
        const int row = dt * 16 + la;
        bfx8 vf = *(const bfx8*)(Vb + (size_t)row * 128 + (((f << 2) + lg) ^ sw) * 16);
        acc[0][dt] = __builtin_amdgcn_mfma_f32_16x16x32_bf16(vf, pf[0], acc[0][dt], 0, 0, 0);
        acc[1][dt] = __builtin_amdgcn_mfma_f32_16x16x32_bf16(vf, pf[1], acc[1][dt], 0, 0, 0);
      }
      __builtin_amdgcn_s_setprio(0);
    }
    cur ^= 1;
  }

  // ---- finalize per-group lsum (cross-lane, once) ----
#pragma unroll
  for (int qt = 0; qt < 2; qt++) {
    lsum[qt] += __shfl_xor(lsum[qt], 16);
    lsum[qt] += __shfl_xor(lsum[qt], 32);
  }

  // ---- merge group partials via LDS scratch (KV buffers dead) ----
  __syncthreads();
  const int gi = wv4 * 64 + lane;                  // 0..255 within group
  float* scr = (float*)sm + (size_t)gi * 36;       // 36 KB
  if (g == 1) {
#pragma unroll
    for (int qt = 0; qt < 2; qt++)
#pragma unroll
      for (int dt = 0; dt < 4; dt++)
#pragma unroll
        for (int j = 0; j < 4; j++) scr[qt * 16 + dt * 4 + j] = acc[qt][dt][j];
    scr[32] = mold[0]; scr[33] = mold[1];
    scr[34] = lsum[0]; scr[35] = lsum[1];
  }
  __syncthreads();
  if (g == 0) {
#pragma unroll
    for (int qt = 0; qt < 2; qt++) {
      const float mB = scr[32 + qt], lB = scr[34 + qt];
      const float mN = fmaxf(mold[qt], mB);
      const float sA = exp2f(mold[qt] - mN);
      const float sB = exp2f(mB - mN);
      const float inv = 1.f / (lsum[qt] * sA + lB * sB);
      u16* ob = att + (size_t)(b * SS + q0 + wv4 * 32 + qt * 16 + la) * DM + h * DK + lg * 4;
#pragma unroll
      for (int dt = 0; dt < 4; dt++) {
        float o0 = (acc[qt][dt][0] * sA + scr[qt * 16 + dt * 4 + 0] * sB) * inv;
        float o1 = (acc[qt][dt][1] * sA + scr[qt * 16 + dt * 4 + 1] * sB) * inv;
        float o2 = (acc[qt][dt][2] * sA + scr[qt * 16 + dt * 4 + 2] * sB) * inv;
        float o3 = (acc[qt][dt][3] * sA + scr[qt * 16 + dt * 4 + 3] * sB) * inv;
        uint2 o;
        o.x = pk2bf(o0, o1);
        o.y = pk2bf(o2, o3);
        *(uint2*)(ob + dt * 16) = o;
      }
    }
  }
}

// ---------------------------------------------------------------------------
extern "C" void kernel_launch(void* const* d_in, const int* in_sizes, int n_in,
                              void* d_out, int out_size, void* d_ws, size_t ws_size,
                              hipStream_t stream) {
  const float* x    = (const float*)d_in[0];
  const float* wq   = (const float*)d_in[1];
  const float* bq   = (const float*)d_in[2];
  const float* wk   = (const float*)d_in[3];
  const float* bk   = (const float*)d_in[4];
  const float* wv   = (const float*)d_in[5];
  const float* bv   = (const float*)d_in[6];
  const float* wo   = (const float*)d_in[7];
  const float* bo   = (const float*)d_in[8];
  const float* w1   = (const float*)d_in[9];
  const float* b1   = (const float*)d_in[10];
  const float* w2   = (const float*)d_in[11];
  const float* b2   = (const float*)d_in[12];
  const float* ln1g = (const float*)d_in[13];
  const float* ln1b = (const float*)d_in[14];
  const float* ln2g = (const float*)d_in[15];
  const float* ln2b = (const float*)d_in[16];
  float* out = (float*)d_out;

  char* w = (char*)d_ws;
  const size_t MB = 1024ull * 1024ull;
  u16*   wqkv = (u16*)(w + 0 * MB);   // [3072][1024] bf16 (Q,K,V stacked)
  u16*   wot  = (u16*)(w + 6 * MB);   // [1024][1024]
  u16*   w1t  = (u16*)(w + 8 * MB);   // [4096][1024]
  u16*   w2t  = (u16*)(w + 16 * MB);  // [1024][4096]
  float* x2   = (float*)(w + 24 * MB);// [8192][1024] f32
  u16*   hb   = (u16*)(w + 56 * MB);  // [8192][1024] (h, then h2)
  u16*   qb   = (u16*)(w + 72 * MB);  // [8192][1024]; K at +8M u16, V^T at +16M u16
  u16*   kb   = (u16*)(w + 88 * MB);
  u16*   vtb  = (u16*)(w + 104 * MB); // [4][16][64][2048] V^T per head
  u16*   atb  = (u16*)(w + 120 * MB); // [8192][1024]
  u16*   ffb  = (u16*)(w + 72 * MB);  // [8192][4096] overlays q/k/vt/att

  // 1) ALL weight transposes in one launch (f32 -> bf16 W^T)
  k_transpose_all<<<dim3(12288), 256, 0, stream>>>(wq, wk, wv, wo, w1, w2,
                                                   wqkv, wot, w1t, w2t);

  // 2) LN1: x -> h (bf16)
  k_layernorm<<<MROWS / 4, 256, 0, stream>>>(x, ln1g, ln1b, hb);

  // 3) fused QKV projection: BM=256, BN=128 -> 24x32 = 768 blocks
  k_gemm_bt<4><<<dim3(24, 32), 512, 0, stream>>>(hb, wqkv, bq, bk, bv, nullptr, qb,
                                                 MROWS, 3 * DM, DM);

  // 4) causal flash attention (swapped QK^T, split-KV, 8 waves)
  k_attn<<<dim3(1024), 512, 0, stream>>>(qb, kb, vtb, atb);

  // 5) O projection + residual (f32 x2): 8x32 = 256 blocks
  k_gemm_bt<1><<<dim3(8, 32), 512, 0, stream>>>(atb, wot, bo, nullptr, nullptr, x, x2,
                                                MROWS, DM, DM);

  // 6) LN2: x2 -> h2 (bf16, reuse hb)
  k_layernorm<<<MROWS / 4, 256, 0, stream>>>(x2, ln2g, ln2b, hb);

  // 7) FF1 + GELU: 32x32 = 1024 blocks
  k_gemm_bt<2><<<dim3(32, 32), 512, 0, stream>>>(hb, w1t, b1, nullptr, nullptr, nullptr, ffb,
                                                 MROWS, DFF, DM);

  // 8) FF2 + residual -> d_out (f32): 8x32 = 256 blocks
  k_gemm_bt<1><<<dim3(8, 32), 512, 0, stream>>>(ffb, w2t, b2, nullptr, nullptr, x2, out,
                                                MROWS, DM, DFF);
}

// Round 12
// 445.549 us; speedup vs baseline: 1.4136x; 1.4136x over previous
//
#include <hip/hip_runtime.h>
#include <hip/hip_bf16.h>

#define DM   1024
#define DFF  4096
#define NB   4
#define SS   2048
#define NH   16
#define DK   64
#define MROWS (NB*SS)   // 8192

typedef __attribute__((ext_vector_type(8)))  short bfx8;
typedef __attribute__((ext_vector_type(4)))  float fx4;
typedef __attribute__((ext_vector_type(16))) float fx16;
typedef unsigned int u32;
typedef unsigned short u16;

static __device__ __forceinline__ u16 f2bf(float f) {
  union { __hip_bfloat16 h; u16 u; } cv;
  cv.h = __float2bfloat16(f);
  return cv.u;
}
static __device__ __forceinline__ u32 pk2bf(float a, float b) {
  return (u32)f2bf(a) | ((u32)f2bf(b) << 16);
}

static __device__ __forceinline__ void async16(void* lds, const void* g) {
  typedef const __attribute__((address_space(1))) unsigned int* gp_t;
  typedef __attribute__((address_space(3))) unsigned int* lp_t;
  __builtin_amdgcn_global_load_lds((gp_t)g, (lp_t)lds, 16, 0, 0);
}

// ------------- ALL weight transposes in one launch: out[n][k] = in[k][n] ----
__global__ __launch_bounds__(256) void k_transpose_all(
    const float* __restrict__ wq, const float* __restrict__ wk,
    const float* __restrict__ wv, const float* __restrict__ wo,
    const float* __restrict__ w1, const float* __restrict__ w2,
    u16* __restrict__ wqkv, u16* __restrict__ wot,
    u16* __restrict__ w1t,  u16* __restrict__ w2t) {
  __shared__ float t[32][33];
  const int idx = blockIdx.x;
  const float* in; u16* out; int K, N, bx, by;
  if (idx < 4096) {
    const int m = idx >> 10, tl = idx & 1023;
    in  = (m == 0) ? wq : (m == 1) ? wk : (m == 2) ? wv : wo;
    out = (m < 3) ? (wqkv + (size_t)m * 1024 * 1024) : wot;
    K = 1024; N = 1024; bx = tl & 31; by = tl >> 5;
  } else if (idx < 8192) {
    const int tl = idx - 4096;
    in = w1; out = w1t; K = 1024; N = 4096; bx = tl & 127; by = tl >> 7;
  } else {
    const int tl = idx - 8192;
    in = w2; out = w2t; K = 4096; N = 1024; bx = tl & 31; by = tl >> 5;
  }
  const int n0 = bx * 32, k0 = by * 32;
  const int tx = threadIdx.x & 31, ty = threadIdx.x >> 5;  // 32 x 8
#pragma unroll
  for (int j = 0; j < 4; j++)
    t[ty + j * 8][tx] = in[(size_t)(k0 + ty + j * 8) * N + n0 + tx];
  __syncthreads();
#pragma unroll
  for (int j = 0; j < 4; j++)
    out[(size_t)(n0 + ty + j * 8) * K + k0 + tx] = f2bf(t[tx][ty + j * 8]);
}

// ---------------- layernorm: f32 in -> bf16 out, one wave per row ----------
__global__ __launch_bounds__(256) void k_layernorm(const float* __restrict__ x,
                                                   const float* __restrict__ g,
                                                   const float* __restrict__ b,
                                                   u16* __restrict__ out) {
  const int row  = blockIdx.x * 4 + (threadIdx.x >> 6);
  const int lane = threadIdx.x & 63;
  const float* xr = x + (size_t)row * DM;
  float4 vb[4];
  float s = 0.f, s2 = 0.f;
#pragma unroll
  for (int j = 0; j < 4; j++) {
    float4 v = *(const float4*)(xr + j * 256 + lane * 4);
    vb[j] = v;
    s  += v.x + v.y + v.z + v.w;
    s2 += v.x * v.x + v.y * v.y + v.z * v.z + v.w * v.w;
  }
#pragma unroll
  for (int off = 1; off < 64; off <<= 1) {
    s  += __shfl_xor(s,  off);
    s2 += __shfl_xor(s2, off);
  }
  const float mu   = s * (1.f / DM);
  const float var  = s2 * (1.f / DM) - mu * mu;
  const float rstd = rsqrtf(var + 1e-5f);
  u16* orow = out + (size_t)row * DM;
#pragma unroll
  for (int j = 0; j < 4; j++) {
    const int col = j * 256 + lane * 4;
    uint2 o;
    o.x = pk2bf((vb[j].x - mu) * rstd * g[col + 0] + b[col + 0],
                (vb[j].y - mu) * rstd * g[col + 1] + b[col + 1]);
    o.y = pk2bf((vb[j].z - mu) * rstd * g[col + 2] + b[col + 2],
                (vb[j].w - mu) * rstd * g[col + 3] + b[col + 3]);
    *(uint2*)(orow + col) = o;
  }
}

// ---------------- GEMM: C[M,N] = A[M,K](bf16) @ BT[N,K](bf16)^T + bias -----
// mfma_f32_32x32x16_bf16. BM=256, BN=128, 8 waves (4M x 2N), wave tile 64x64
// = 2x2 fragments of 32x32 (acc 4 x fx16). BK=32, RING-3 LDS (72 KB -> 2
// blocks/CU), ONE barrier per K-tile, counted vmcnt(3) (3 loads/tile, retire
// t+1 at end of t). 64B LDS rows, XOR swizzle slot^((row>>1)&3) both sides.
// bf16 epilogues bounce via LDS for full-sector stores (r10, proven).
// C/D layout (verified m74/m101): col=lane&31, row=(reg&3)+8*(reg>>2)+4*(lane>>5).
// EPI: 1 = f32 out (+res), 2 = bf16 gelu out, 4 = fused QKV
template <int EPI>
__global__ __launch_bounds__(512, 4) void k_gemm_bt(const u16* __restrict__ A,
                                                    const u16* __restrict__ BT,
                                                    const float* __restrict__ bias0,
                                                    const float* __restrict__ bias1,
                                                    const float* __restrict__ bias2,
                                                    const float* __restrict__ res,
                                                    void* __restrict__ outp,
                                                    int M, int N, int K) {
  constexpr int ABUF = 256 * 32 * 2;   // 16 KB
  constexpr int BBUF = 128 * 32 * 2;   // 8 KB
  __shared__ char Al[3 * ABUF];        // 48 KB (reused as epilogue bounce)
  __shared__ char Bl[3 * BBUF];        // 24 KB

  const int tid = threadIdx.x, wave = tid >> 6, lane = tid & 63;
  const int nwg = gridDim.x * gridDim.y;
  const int bid = blockIdx.y * gridDim.x + blockIdx.x;
  const int swz = (bid & 7) * (nwg >> 3) + (bid >> 3);
  const int m0 = (swz / gridDim.x) * 256, n0 = (swz % gridDim.x) * 128;
  const int wm = (wave >> 1) * 64, wn = (wave & 1) * 64;
  const int l31 = lane & 31, l5 = lane >> 5;
  const int psw = (l31 >> 1) & 3;      // read-side XOR swizzle (row>>1)&3

  fx16 acc[2][2];
#pragma unroll
  for (int i = 0; i < 2; i++)
#pragma unroll
    for (int j = 0; j < 2; j++)
#pragma unroll
      for (int e = 0; e < 16; e++) acc[i][j][e] = 0.f;

  // staging: thread tid -> LDS phys (row=tid>>2, slot=tid&3) per 8KB chunk;
  // fetch logical slot = (tid&3) ^ ((tid>>3)&3)  (inverse of read swizzle)
  const int arow = tid >> 2;                       // 0..127
  const int aslot = ((tid & 3) ^ ((tid >> 3) & 3)) * 8;
  const u16* gA = A  + (size_t)(m0 + arow) * K + aslot;
  const u16* gB = BT + (size_t)(n0 + arow) * K + aslot;

  auto stageAB = [&](int buf, int kt) {
    async16(Al + buf * ABUF + wave * 1024,        gA + kt);
    async16(Al + buf * ABUF + 8192 + wave * 1024, gA + (size_t)128 * K + kt);
    async16(Bl + buf * BBUF + wave * 1024,        gB + kt);
  };

  const int nk = K >> 5;
  stageAB(0, 0);
  stageAB(1, 32);
  asm volatile("s_waitcnt vmcnt(3)" ::: "memory");   // retire tile 0
  __builtin_amdgcn_sched_barrier(0);
  __builtin_amdgcn_s_barrier();
  asm volatile("" ::: "memory");

  int cur = 0;
  for (int t = 0; t < nk; ++t) {
    const char* Ab = (const char*)Al + cur * ABUF;
    const char* Bb = (const char*)Bl + cur * BBUF;
    bfx8 av[2][2], bv[2][2];   // [frag][k-half]
#pragma unroll
    for (int mi = 0; mi < 2; mi++)
#pragma unroll
      for (int kk = 0; kk < 2; kk++)
        av[mi][kk] = *(const bfx8*)(Ab + (wm + mi * 32 + l31) * 64 +
                                    (((kk << 1) | l5) ^ psw) * 16);
#pragma unroll
    for (int ni = 0; ni < 2; ni++)
#pragma unroll
      for (int kk = 0; kk < 2; kk++)
        bv[ni][kk] = *(const bfx8*)(Bb + (wn + ni * 32 + l31) * 64 +
                                    (((kk << 1) | l5) ^ psw) * 16);
    int nb = cur + 2; if (nb >= 3) nb -= 3;
    if (t + 2 < nk) stageAB(nb, (t + 2) << 5);

    __builtin_amdgcn_s_setprio(1);
#pragma unroll
    for (int kk = 0; kk < 2; kk++)
#pragma unroll
      for (int mi = 0; mi < 2; mi++)
#pragma unroll
        for (int ni = 0; ni < 2; ni++)
          acc[mi][ni] = __builtin_amdgcn_mfma_f32_32x32x16_bf16(
              av[mi][kk], bv[ni][kk], acc[mi][ni], 0, 0, 0);
    __builtin_amdgcn_s_setprio(0);

    const int rem = nk - 1 - t;
    if (rem >= 2)      { asm volatile("s_waitcnt vmcnt(3)" ::: "memory"); }
    else if (rem == 1) { asm volatile("s_waitcnt vmcnt(0)" ::: "memory"); }
    __builtin_amdgcn_sched_barrier(0);
    if (rem > 0) __builtin_amdgcn_s_barrier();
    asm volatile("" ::: "memory");
    cur = (cur + 1 == 3) ? 0 : cur + 1;
  }
  __syncthreads();   // LDS now dead; safe to reuse as bounce scratch

  // ============ epilogue ============
  // Per-wave 32x32 f32 bounce tile, row stride 33 (4224 B/wave, 8x = 33.8 KB)
  float* scr = (float*)(void*)Al + (size_t)wave * (33 * 32);

  auto emit32 = [&](u16* base, size_t ld, int mrow0, int ncol0, const float* v) {
#pragma unroll
    for (int r = 0; r < 16; r++)
      scr[((r & 3) + 8 * (r >> 2) + 4 * l5) * 33 + l31] = v[r];
    asm volatile("s_waitcnt lgkmcnt(0)" ::: "memory");
    __builtin_amdgcn_sched_barrier(0);
#pragma unroll
    for (int i = 0; i < 4; i++) {
      float4 q = *(const float4*)&scr[l31 * 33 + l5 * 16 + i * 4];
      uint2 o;
      o.x = pk2bf(q.x, q.y);
      o.y = pk2bf(q.z, q.w);
      *(uint2*)(base + (size_t)(mrow0 + l31) * ld + ncol0 + l5 * 16 + i * 4) = o;
    }
    asm volatile("s_waitcnt lgkmcnt(0)" ::: "memory");
    __builtin_amdgcn_sched_barrier(0);
  };

  if constexpr (EPI == 4) {
    const int reg = n0 >> 10;  // 0=Q, 1=K, 2=V (block-uniform)
    const float* bp = (reg == 0) ? bias0 : (reg == 1) ? bias1 : bias2;
    if (reg < 2) {
      u16* base = (u16*)outp + (size_t)reg * (8u * 1024 * 1024);
#pragma unroll
      for (int mi = 0; mi < 2; mi++)
#pragma unroll
        for (int ni = 0; ni < 2; ni++) {
          const float bs = bp[(n0 + wn + ni * 32 + l31) & 1023];
          float v[16];
#pragma unroll
          for (int r = 0; r < 16; r++) v[r] = acc[mi][ni][r] + bs;
          emit32(base, 1024, m0 + wm + mi * 32, (n0 + wn + ni * 32) & 1023, v);
        }
    } else {  // V^T: out[((bb*NH+h)*DK+d)*SS + s]
#pragma unroll
      for (int mi = 0; mi < 2; mi++) {
        const int mbase = m0 + wm + mi * 32;
        const int bb2 = mbase >> 11;
#pragma unroll
        for (int ni = 0; ni < 2; ni++) {
          const int nl = (n0 + wn + ni * 32 + l31) & 1023;
          const float bs = bp[nl];
          const int hh = nl >> 6, d = nl & 63;
          u16* vph = (u16*)outp + 16u * 1024 * 1024 +
                     (((size_t)bb2 * NH + hh) * DK + d) * SS;
#pragma unroll
          for (int rg = 0; rg < 4; rg++) {
            const int s = (mbase + 8 * rg + 4 * l5) & 2047;
            uint2 o;
            o.x = pk2bf(acc[mi][ni][rg * 4 + 0] + bs, acc[mi][ni][rg * 4 + 1] + bs);
            o.y = pk2bf(acc[mi][ni][rg * 4 + 2] + bs, acc[mi][ni][rg * 4 + 3] + bs);
            *(uint2*)(vph + s) = o;
          }
        }
      }
    }
  } else if constexpr (EPI == 2) {
#pragma unroll
    for (int mi = 0; mi < 2; mi++)
#pragma unroll
      for (int ni = 0; ni < 2; ni++) {
        const float bs = bias0[n0 + wn + ni * 32 + l31];
        float v[16];
#pragma unroll
        for (int r = 0; r < 16; r++) {
          const float val = acc[mi][ni][r] + bs;
          v[r] = 0.5f * val * (1.f + erff(val * 0.70710678118f));
        }
        emit32((u16*)outp, N, m0 + wm + mi * 32, n0 + wn + ni * 32, v);
      }
  } else {  // EPI == 1: f32 out + residual
#pragma unroll
    for (int ni = 0; ni < 2; ni++) {
      const int n = n0 + wn + ni * 32 + l31;
      const float bs = bias0[n];
#pragma unroll
      for (int mi = 0; mi < 2; mi++) {
#pragma unroll
        for (int r = 0; r < 16; r++) {
          const int row = (r & 3) + 8 * (r >> 2) + 4 * l5;
          const size_t idx = (size_t)(m0 + wm + mi * 32 + row) * N + n;
          ((float*)outp)[idx] = res[idx] + acc[mi][ni][r] + bs;
        }
      }
    }
  }
}

// ---------------- causal flash attention, swapped-QK^T, split-KV ----------
// (unchanged from round 10 -- proven)
__global__ __launch_bounds__(512, 4) void k_attn(const u16* __restrict__ q,
                                                 const u16* __restrict__ k,
                                                 const u16* __restrict__ vt,
                                                 u16* __restrict__ att) {
  __shared__ char sm[65536];
  const int bid = blockIdx.x;
  const int bq = 15 - (bid >> 6);
  const int bh = bid & 63;
  const int b = bh >> 4, h = bh & 15;

  const int tid = threadIdx.x, wave = tid >> 6, lane = tid & 63;
  const int g = wave >> 2, wv4 = wave & 3;
  const int la = lane & 15, lg = lane >> 4;
  const int q0 = bq * 128;

  bfx8 qf[2][2];
#pragma unroll
  for (int qt = 0; qt < 2; qt++) {
    const u16* qp = q + (size_t)(b * SS + q0 + wv4 * 32 + qt * 16 + la) * DM + h * DK + lg * 8;
#pragma unroll
    for (int f = 0; f < 2; f++) qf[qt][f] = *(const bfx8*)(qp + f * 32);
  }

  fx4 acc[2][4];
#pragma unroll
  for (int qt = 0; qt < 2; qt++)
#pragma unroll
    for (int dt = 0; dt < 4; dt++) acc[qt][dt] = fx4{0.f, 0.f, 0.f, 0.f};
  float mold[2] = {-10000.f, -10000.f};
  float lsum[2] = {0.f, 0.f};

  const int srow = lane >> 3;
  const int sslot = (lane & 7) ^ srow;
  const u16* kg0 = k  + (size_t)(b * SS + wv4 * 16 + srow) * DM + h * DK + sslot * 8;
  const u16* vg0 = vt + (size_t)((b * NH + h) * DK + wv4 * 16 + srow) * SS + sslot * 8;
  char* kbase = sm + g * 32768 + wv4 * 2048;
  char* vbase = sm + g * 32768 + 16384 + wv4 * 2048;

  const float c1 = 0.18033688f;
  const int niter = bq + 1;

  auto stage = [&](int buf, int i) {
    const int c0 = (2 * i + g) * 64;
#pragma unroll
    for (int j = 0; j < 2; j++)
      async16(kbase + buf * 8192 + j * 1024, kg0 + (size_t)(c0 + j * 8) * DM);
#pragma unroll
    for (int j = 0; j < 2; j++)
      async16(vbase + buf * 8192 + j * 1024, vg0 + (size_t)(j * 8) * SS + c0);
  };

  stage(0, 0);
  int cur = 0;
  const int sw = la & 7;

  for (int i = 0; i < niter; i++) {
    __syncthreads();
    if (i + 1 < niter) stage(cur ^ 1, i + 1);
    const int c0 = (2 * i + g) * 64;
    const bool msk = (i == niter - 1);
    const char* Kb = sm + g * 32768 + cur * 8192;
    const char* Vb = sm + g * 32768 + 16384 + cur * 8192;

    fx4 st[2][4];
    __builtin_amdgcn_s_setprio(1);
#pragma unroll
    for (int t = 0; t < 4; t++) {
      const char* kr = Kb + (size_t)(t * 16 + la) * 128;
      bfx8 kf0 = *(const bfx8*)(kr + ((0 + lg) ^ sw) * 16);
      bfx8 kf1 = *(const bfx8*)(kr + ((4 + lg) ^ sw) * 16);
#pragma unroll
      for (int qt = 0; qt < 2; qt++) {
        fx4 z = fx4{0.f, 0.f, 0.f, 0.f};
        z = __builtin_amdgcn_mfma_f32_16x16x32_bf16(kf0, qf[qt][0], z, 0, 0, 0);
        z = __builtin_amdgcn_mfma_f32_16x16x32_bf16(kf1, qf[qt][1], z, 0, 0, 0);
        st[qt][t] = z;
      }
    }
    __builtin_amdgcn_s_setprio(0);

    if (msk) {
#pragma unroll
      for (int qt = 0; qt < 2; qt++) {
        const int qir = q0 + wv4 * 32 + qt * 16 + la;
#pragma unroll
        for (int t = 0; t < 4; t++)
#pragma unroll
          for (int r = 0; r < 4; r++)
            if (c0 + t * 16 + lg * 4 + r > qir) st[qt][t][r] = -1e9f;
      }
    }

    float lmx[2];
#pragma unroll
    for (int qt = 0; qt < 2; qt++) {
      float mx = fmaxf(fmaxf(st[qt][0][0], st[qt][0][1]), fmaxf(st[qt][0][2], st[qt][0][3]));
#pragma unroll
      for (int t = 1; t < 4; t++)
        mx = fmaxf(mx, fmaxf(fmaxf(st[qt][t][0], st[qt][t][1]), fmaxf(st[qt][t][2], st[qt][t][3])));
      lmx[qt] = mx * c1;
    }
    const bool def = (lmx[0] <= mold[0] + 8.f) && (lmx[1] <= mold[1] + 8.f);
    if (!__all(def)) {
#pragma unroll
      for (int qt = 0; qt < 2; qt++) {
        float mx = lmx[qt];
        mx = fmaxf(mx, __shfl_xor(mx, 16));
        mx = fmaxf(mx, __shfl_xor(mx, 32));
        const float mnew  = fmaxf(mold[qt], mx);
        const float scale = exp2f(mold[qt] - mnew);
        mold[qt] = mnew;
        lsum[qt] *= scale;
#pragma unroll
        for (int dt = 0; dt < 4; dt++) {
          acc[qt][dt][0] *= scale; acc[qt][dt][1] *= scale;
          acc[qt][dt][2] *= scale; acc[qt][dt][3] *= scale;
        }
      }
    }
    u32 W[2][4][2];
#pragma unroll
    for (int qt = 0; qt < 2; qt++) {
      float ps = 0.f;
#pragma unroll
      for (int t = 0; t < 4; t++) {
        float p0 = exp2f(fmaf(st[qt][t][0], c1, -mold[qt]));
        float p1 = exp2f(fmaf(st[qt][t][1], c1, -mold[qt]));
        float p2 = exp2f(fmaf(st[qt][t][2], c1, -mold[qt]));
        float p3 = exp2f(fmaf(st[qt][t][3], c1, -mold[qt]));
        ps += (p0 + p1) + (p2 + p3);
        W[qt][t][0] = pk2bf(p0, p1);
        W[qt][t][1] = pk2bf(p2, p3);
      }
      lsum[qt] += ps;
    }

    const int sLo = la + ((lg & 1) << 5);
    const int sHi = sLo + 16;
    const bool tHi = (lg >> 1) & 1;
#pragma unroll
    for (int f = 0; f < 2; f++) {
      bfx8 pf[2];
#pragma unroll
      for (int qt = 0; qt < 2; qt++) {
        const u32 a0 = __shfl(W[qt][2 * f][0], sLo), b0 = __shfl(W[qt][2 * f + 1][0], sLo);
        const u32 a1 = __shfl(W[qt][2 * f][1], sLo), b1 = __shfl(W[qt][2 * f + 1][1], sLo);
        const u32 a2 = __shfl(W[qt][2 * f][0], sHi), b2 = __shfl(W[qt][2 * f + 1][0], sHi);
        const u32 a3 = __shfl(W[qt][2 * f][1], sHi), b3 = __shfl(W[qt][2 * f + 1][1], sHi);
        union { u32 u[4]; bfx8 v; } pu;
        pu.u[0] = tHi ? b0 : a0;
        pu.u[1] = tHi ? b1 : a1;
        pu.u[2] = tHi ? b2 : a2;
        pu.u[3] = tHi ? b3 : a3;
        pf[qt] = pu.v;
      }
      __builtin_amdgcn_s_setprio(1);
#pragma unroll
      for (int dt = 0; dt < 4; dt++) {
        const int row = dt * 16 + la;
        bfx8 vf = *(const bfx8*)(Vb + (size_t)row * 128 + (((f << 2) + lg) ^ sw) * 16);
        acc[0][dt] = __builtin_amdgcn_mfma_f32_16x16x32_bf16(vf, pf[0], acc[0][dt], 0, 0, 0);
        acc[1][dt] = __builtin_amdgcn_mfma_f32_16x16x32_bf16(vf, pf[1], acc[1][dt], 0, 0, 0);
      }
      __builtin_amdgcn_s_setprio(0);
    }
    cur ^= 1;
  }

#pragma unroll
  for (int qt = 0; qt < 2; qt++) {
    lsum[qt] += __shfl_xor(lsum[qt], 16);
    lsum[qt] += __shfl_xor(lsum[qt], 32);
  }

  __syncthreads();
  const int gi = wv4 * 64 + lane;
  float* scr = (float*)sm + (size_t)gi * 36;
  if (g == 1) {
#pragma unroll
    for (int qt = 0; qt < 2; qt++)
#pragma unroll
      for (int dt = 0; dt < 4; dt++)
#pragma unroll
        for (int j = 0; j < 4; j++) scr[qt * 16 + dt * 4 + j] = acc[qt][dt][j];
    scr[32] = mold[0]; scr[33] = mold[1];
    scr[34] = lsum[0]; scr[35] = lsum[1];
  }
  __syncthreads();
  if (g == 0) {
#pragma unroll
    for (int qt = 0; qt < 2; qt++) {
      const float mB = scr[32 + qt], lB = scr[34 + qt];
      const float mN = fmaxf(mold[qt], mB);
      const float sA = exp2f(mold[qt] - mN);
      const float sB = exp2f(mB - mN);
      const float inv = 1.f / (lsum[qt] * sA + lB * sB);
      u16* ob = att + (size_t)(b * SS + q0 + wv4 * 32 + qt * 16 + la) * DM + h * DK + lg * 4;
#pragma unroll
      for (int dt = 0; dt < 4; dt++) {
        float o0 = (acc[qt][dt][0] * sA + scr[qt * 16 + dt * 4 + 0] * sB) * inv;
        float o1 = (acc[qt][dt][1] * sA + scr[qt * 16 + dt * 4 + 1] * sB) * inv;
        float o2 = (acc[qt][dt][2] * sA + scr[qt * 16 + dt * 4 + 2] * sB) * inv;
        float o3 = (acc[qt][dt][3] * sA + scr[qt * 16 + dt * 4 + 3] * sB) * inv;
        uint2 o;
        o.x = pk2bf(o0, o1);
        o.y = pk2bf(o2, o3);
        *(uint2*)(ob + dt * 16) = o;
      }
    }
  }
}

// ---------------------------------------------------------------------------
extern "C" void kernel_launch(void* const* d_in, const int* in_sizes, int n_in,
                              void* d_out, int out_size, void* d_ws, size_t ws_size,
                              hipStream_t stream) {
  const float* x    = (const float*)d_in[0];
  const float* wq   = (const float*)d_in[1];
  const float* bq   = (const float*)d_in[2];
  const float* wk   = (const float*)d_in[3];
  const float* bk   = (const float*)d_in[4];
  const float* wv   = (const float*)d_in[5];
  const float* bv   = (const float*)d_in[6];
  const float* wo   = (const float*)d_in[7];
  const float* bo   = (const float*)d_in[8];
  const float* w1   = (const float*)d_in[9];
  const float* b1   = (const float*)d_in[10];
  const float* w2   = (const float*)d_in[11];
  const float* b2   = (const float*)d_in[12];
  const float* ln1g = (const float*)d_in[13];
  const float* ln1b = (const float*)d_in[14];
  const float* ln2g = (const float*)d_in[15];
  const float* ln2b = (const float*)d_in[16];
  float* out = (float*)d_out;

  char* w = (char*)d_ws;
  const size_t MB = 1024ull * 1024ull;
  u16*   wqkv = (u16*)(w + 0 * MB);   // [3072][1024] bf16 (Q,K,V stacked)
  u16*   wot  = (u16*)(w + 6 * MB);   // [1024][1024]
  u16*   w1t  = (u16*)(w + 8 * MB);   // [4096][1024]
  u16*   w2t  = (u16*)(w + 16 * MB);  // [1024][4096]
  float* x2   = (float*)(w + 24 * MB);// [8192][1024] f32
  u16*   hb   = (u16*)(w + 56 * MB);  // [8192][1024] (h, then h2)
  u16*   qb   = (u16*)(w + 72 * MB);  // [8192][1024]; K at +8M u16, V^T at +16M u16
  u16*   kb   = (u16*)(w + 88 * MB);
  u16*   vtb  = (u16*)(w + 104 * MB); // [4][16][64][2048] V^T per head
  u16*   atb  = (u16*)(w + 120 * MB); // [8192][1024]
  u16*   ffb  = (u16*)(w + 72 * MB);  // [8192][4096] overlays q/k/vt/att

  // 1) ALL weight transposes in one launch (f32 -> bf16 W^T)
  k_transpose_all<<<dim3(12288), 256, 0, stream>>>(wq, wk, wv, wo, w1, w2,
                                                   wqkv, wot, w1t, w2t);

  // 2) LN1: x -> h (bf16)
  k_layernorm<<<MROWS / 4, 256, 0, stream>>>(x, ln1g, ln1b, hb);

  // 3) fused QKV projection: BM=256, BN=128 -> 24x32 = 768 blocks
  k_gemm_bt<4><<<dim3(24, 32), 512, 0, stream>>>(hb, wqkv, bq, bk, bv, nullptr, qb,
                                                 MROWS, 3 * DM, DM);

  // 4) causal flash attention (swapped QK^T, split-KV, 8 waves)
  k_attn<<<dim3(1024), 512, 0, stream>>>(qb, kb, vtb, atb);

  // 5) O projection + residual (f32 x2): 8x32 = 256 blocks
  k_gemm_bt<1><<<dim3(8, 32), 512, 0, stream>>>(atb, wot, bo, nullptr, nullptr, x, x2,
                                                MROWS, DM, DM);

  // 6) LN2: x2 -> h2 (bf16, reuse hb)
  k_layernorm<<<MROWS / 4, 256, 0, stream>>>(x2, ln2g, ln2b, hb);

  // 7) FF1 + GELU: 32x32 = 1024 blocks
  k_gemm_bt<2><<<dim3(32, 32), 512, 0, stream>>>(hb, w1t, b1, nullptr, nullptr, nullptr, ffb,
                                                 MROWS, DFF, DM);

  // 8) FF2 + residual -> d_out (f32): 8x32 = 256 blocks
  k_gemm_bt<1><<<dim3(8, 32), 512, 0, stream>>>(ffb, w2t, b2, nullptr, nullptr, x2, out,
                                                MROWS, DM, DFF);
}

// Round 13
// 431.104 us; speedup vs baseline: 1.4610x; 1.0335x over previous
//
#include <hip/hip_runtime.h>
#include <hip/hip_bf16.h>

#define DM   1024
#define DFF  4096
#define NB   4
#define SS   2048
#define NH   16
#define DK   64
#define MROWS (NB*SS)   // 8192

typedef __attribute__((ext_vector_type(8)))  short bfx8;
typedef __attribute__((ext_vector_type(4)))  float fx4;
typedef __attribute__((ext_vector_type(16))) float fx16;
typedef unsigned int u32;
typedef unsigned short u16;

static __device__ __forceinline__ u16 f2bf(float f) {
  union { __hip_bfloat16 h; u16 u; } cv;
  cv.h = __float2bfloat16(f);
  return cv.u;
}
static __device__ __forceinline__ u32 pk2bf(float a, float b) {
  return (u32)f2bf(a) | ((u32)f2bf(b) << 16);
}

static __device__ __forceinline__ void async16(void* lds, const void* g) {
  typedef const __attribute__((address_space(1))) unsigned int* gp_t;
  typedef __attribute__((address_space(3))) unsigned int* lp_t;
  __builtin_amdgcn_global_load_lds((gp_t)g, (lp_t)lds, 16, 0, 0);
}

// ------------- ALL weight transposes in one launch: out[n][k] = in[k][n] ----
__global__ __launch_bounds__(256) void k_transpose_all(
    const float* __restrict__ wq, const float* __restrict__ wk,
    const float* __restrict__ wv, const float* __restrict__ wo,
    const float* __restrict__ w1, const float* __restrict__ w2,
    u16* __restrict__ wqkv, u16* __restrict__ wot,
    u16* __restrict__ w1t,  u16* __restrict__ w2t) {
  __shared__ float t[32][33];
  const int idx = blockIdx.x;
  const float* in; u16* out; int K, N, bx, by;
  if (idx < 4096) {
    const int m = idx >> 10, tl = idx & 1023;
    in  = (m == 0) ? wq : (m == 1) ? wk : (m == 2) ? wv : wo;
    out = (m < 3) ? (wqkv + (size_t)m * 1024 * 1024) : wot;
    K = 1024; N = 1024; bx = tl & 31; by = tl >> 5;
  } else if (idx < 8192) {
    const int tl = idx - 4096;
    in = w1; out = w1t; K = 1024; N = 4096; bx = tl & 127; by = tl >> 7;
  } else {
    const int tl = idx - 8192;
    in = w2; out = w2t; K = 4096; N = 1024; bx = tl & 31; by = tl >> 5;
  }
  const int n0 = bx * 32, k0 = by * 32;
  const int tx = threadIdx.x & 31, ty = threadIdx.x >> 5;  // 32 x 8
#pragma unroll
  for (int j = 0; j < 4; j++)
    t[ty + j * 8][tx] = in[(size_t)(k0 + ty + j * 8) * N + n0 + tx];
  __syncthreads();
#pragma unroll
  for (int j = 0; j < 4; j++)
    out[(size_t)(n0 + ty + j * 8) * K + k0 + tx] = f2bf(t[tx][ty + j * 8]);
}

// ---------------- layernorm: f32 in -> bf16 out, one wave per row ----------
__global__ __launch_bounds__(256) void k_layernorm(const float* __restrict__ x,
                                                   const float* __restrict__ g,
                                                   const float* __restrict__ b,
                                                   u16* __restrict__ out) {
  const int row  = blockIdx.x * 4 + (threadIdx.x >> 6);
  const int lane = threadIdx.x & 63;
  const float* xr = x + (size_t)row * DM;
  float4 vb[4];
  float s = 0.f, s2 = 0.f;
#pragma unroll
  for (int j = 0; j < 4; j++) {
    float4 v = *(const float4*)(xr + j * 256 + lane * 4);
    vb[j] = v;
    s  += v.x + v.y + v.z + v.w;
    s2 += v.x * v.x + v.y * v.y + v.z * v.z + v.w * v.w;
  }
#pragma unroll
  for (int off = 1; off < 64; off <<= 1) {
    s  += __shfl_xor(s,  off);
    s2 += __shfl_xor(s2, off);
  }
  const float mu   = s * (1.f / DM);
  const float var  = s2 * (1.f / DM) - mu * mu;
  const float rstd = rsqrtf(var + 1e-5f);
  u16* orow = out + (size_t)row * DM;
#pragma unroll
  for (int j = 0; j < 4; j++) {
    const int col = j * 256 + lane * 4;
    uint2 o;
    o.x = pk2bf((vb[j].x - mu) * rstd * g[col + 0] + b[col + 0],
                (vb[j].y - mu) * rstd * g[col + 1] + b[col + 1]);
    o.y = pk2bf((vb[j].z - mu) * rstd * g[col + 2] + b[col + 2],
                (vb[j].w - mu) * rstd * g[col + 3] + b[col + 3]);
    *(uint2*)(orow + col) = o;
  }
}

// ======================= m201-template GEMM (256x256) =======================
// C[M,N] = A[M,K] @ BT[N,K]^T + bias. 8 waves (2M x 4N), wave tile 128x64
// (8x4 frags of 16x16x32, acc 128 VGPR). BK=64, double-buffered 128 KB LDS in
// phase-aligned 16 KB chunks: A[buf][mh][kk][128r'][32c], B[buf][nh][kk][128r''][32c]
// (64B rows, zero-conflict swizzle slot^((la>>1)&3), proven r8/r10).
// Per K-tile 4 phases = C-quadrants (mh,nh): each {ds_read; stage 1 chunk of
// t+1; [counted vmcnt]; barrier; lgkmcnt(0); setprio; 16 MFMA; setprio; barrier}.
// vmcnt(4) at p1/p3 keeps 4 loads in flight (never drains mid-loop).
// EPI: 2 = bf16 gelu out, 4 = fused QKV (Q,K row-major; V per-head-transposed)
template <int EPI>
__global__ __launch_bounds__(512, 2) void k_gemm256(const u16* __restrict__ A,
                                                    const u16* __restrict__ BT,
                                                    const float* __restrict__ bias0,
                                                    const float* __restrict__ bias1,
                                                    const float* __restrict__ bias2,
                                                    void* __restrict__ outp,
                                                    int M, int N, int K) {
  __shared__ char Sl[131072];   // A: [0,64K) ; B: [64K,128K)

  const int tid = threadIdx.x, wave = tid >> 6, lane = tid & 63;
  const int nwg = gridDim.x * gridDim.y;
  const int bid = blockIdx.y * gridDim.x + blockIdx.x;
  const int swz = (bid & 7) * (nwg >> 3) + (bid >> 3);
  const int m0 = (swz / gridDim.x) * 256, n0 = (swz % gridDim.x) * 256;
  const int wr = wave >> 2, wcn = wave & 3;       // 2M x 4N
  const int la = lane & 15, lg = lane >> 4;
  const int psw = (la >> 1) & 3;                  // read-side XOR swizzle

  fx4 acc[8][4];
#pragma unroll
  for (int i = 0; i < 8; i++)
#pragma unroll
    for (int j = 0; j < 4; j++) acc[i][j] = fx4{0.f, 0.f, 0.f, 0.f};

  // ---- staging lane constants (pre-swizzled global source) ----
  const int rp  = wave * 16 + (lane >> 2);        // chunk-local row 0..127
  const int sl  = (lane & 3) ^ ((lane >> 3) & 3); // inverse-swizzled 16B slot
  // A chunk mh: global row = (rp>>6)*128 + mh*64 + (rp&63)
  const int gra = (rp >> 6) * 128 + (rp & 63);    // + mh*64
  // B chunk nh: global row = (rp>>5)*64 + nh*32 + (rp&31)
  const int grb = (rp >> 5) * 64 + (rp & 31);     // + nh*32

  auto stageA = [&](int buf, int mh, int kt) {    // one 16KB chunk (2 async16/wave)
    const u16* src = A + (size_t)(m0 + gra + mh * 64) * K + kt + sl * 8;
    char* dst = Sl + buf * 32768 + mh * 16384 + wave * 1024;
    async16(dst,        src);
    async16(dst + 8192, src + 32);
  };
  auto stageB = [&](int buf, int nh, int kt) {
    const u16* src = BT + (size_t)(n0 + grb + nh * 32) * K + kt + sl * 8;
    char* dst = Sl + 65536 + buf * 32768 + nh * 16384 + wave * 1024;
    async16(dst,        src);
    async16(dst + 8192, src + 32);
  };

  const int nk = K >> 6;
  stageA(0, 0, 0); stageB(0, 0, 0); stageA(0, 1, 0); stageB(0, 1, 0);
  asm volatile("s_waitcnt vmcnt(4)" ::: "memory");   // A0,B0 of tile 0 ready
  __builtin_amdgcn_sched_barrier(0);
  __builtin_amdgcn_s_barrier();
  asm volatile("" ::: "memory");

  bfx8 avv[4][2], bv0[2][2], bv1[2][2];

  auto readA = [&](int buf, int mh) {
    const char* base = Sl + buf * 32768 + mh * 16384;
#pragma unroll
    for (int mtl = 0; mtl < 4; mtl++) {
      const int r = wr * 64 + mtl * 16 + la;
#pragma unroll
      for (int kk = 0; kk < 2; kk++)
        avv[mtl][kk] = *(const bfx8*)(base + kk * 8192 + r * 64 + ((lg ^ psw) * 16));
    }
  };
  auto readB = [&](int buf, int nh, bfx8 (&bv)[2][2]) {
    const char* base = Sl + 65536 + buf * 32768 + nh * 16384;
#pragma unroll
    for (int ntl = 0; ntl < 2; ntl++) {
      const int r = wcn * 32 + ntl * 16 + la;
#pragma unroll
      for (int kk = 0; kk < 2; kk++)
        bv[ntl][kk] = *(const bfx8*)(base + kk * 8192 + r * 64 + ((lg ^ psw) * 16));
    }
  };
  auto quad = [&](int mh, int nh, bfx8 (&bv)[2][2]) {
    __builtin_amdgcn_s_setprio(1);
#pragma unroll
    for (int kk = 0; kk < 2; kk++)
#pragma unroll
      for (int mtl = 0; mtl < 4; mtl++)
#pragma unroll
        for (int ntl = 0; ntl < 2; ntl++)
          acc[mh * 4 + mtl][nh * 2 + ntl] = __builtin_amdgcn_mfma_f32_16x16x32_bf16(
              avv[mtl][kk], bv[ntl][kk], acc[mh * 4 + mtl][nh * 2 + ntl], 0, 0, 0);
    __builtin_amdgcn_s_setprio(0);
  };

#define PH_BAR_PRE()  do { __builtin_amdgcn_sched_barrier(0); __builtin_amdgcn_s_barrier(); \
                           asm volatile("s_waitcnt lgkmcnt(0)" ::: "memory");                \
                           __builtin_amdgcn_sched_barrier(0); } while (0)
#define PH_BAR_POST() do { __builtin_amdgcn_sched_barrier(0); __builtin_amdgcn_s_barrier(); \
                           asm volatile("" ::: "memory"); } while (0)

#pragma unroll 1
  for (int t = 0; t < nk; ++t) {
    const int buf = t & 1, nbuf = buf ^ 1;
    const bool pf = (t + 1 < nk);
    const int nkt = (t + 1) << 6;
    // ---- phase 0: quadrant (0,0). reads: av-lo(8) + bv-nh0(4). stage A0(t+1).
    readA(buf, 0);
    readB(buf, 0, bv0);
    if (pf) stageA(nbuf, 0, nkt);
    PH_BAR_PRE();
    quad(0, 0, bv0);
    PH_BAR_POST();
    // ---- phase 1: quadrant (0,1). reads: bv-nh1(4). stage B0(t+1). vmcnt.
    readB(buf, 1, bv1);
    if (pf) stageB(nbuf, 0, nkt);
    if (pf) { asm volatile("s_waitcnt vmcnt(4)" ::: "memory"); }
    else    { asm volatile("s_waitcnt vmcnt(0)" ::: "memory"); }
    PH_BAR_PRE();
    quad(0, 1, bv1);
    PH_BAR_POST();
    // ---- phase 2: quadrant (1,0). reads: av-hi(8). stage A1(t+1).
    readA(buf, 1);
    if (pf) stageA(nbuf, 1, nkt);
    PH_BAR_PRE();
    quad(1, 0, bv0);
    PH_BAR_POST();
    // ---- phase 3: quadrant (1,1). stage B1(t+1). vmcnt.
    if (pf) {
      stageB(nbuf, 1, nkt);
      asm volatile("s_waitcnt vmcnt(4)" ::: "memory");
    }
    PH_BAR_PRE();
    quad(1, 1, bv1);
    PH_BAR_POST();
  }
  __syncthreads();   // LDS dead -> reuse as epilogue bounce

  // ============ epilogue ============
  const int wm = wr * 128, wn = wcn * 64;
  float* scr = (float*)(void*)Sl + (size_t)wave * (68 * 16);

  auto emit_bf16 = [&](u16* base, size_t ld, int mrow0, int ncol0,
                       const float v[4][4] /*[nt][vv]*/) {
#pragma unroll
    for (int nt = 0; nt < 4; nt++)
#pragma unroll
      for (int vv = 0; vv < 4; vv++)
        scr[(lg * 4 + vv) * 68 + nt * 16 + la] = v[nt][vv];
    asm volatile("s_waitcnt lgkmcnt(0)" ::: "memory");
    __builtin_amdgcn_sched_barrier(0);
#pragma unroll
    for (int p = 0; p < 4; p++) {
      const int r  = p * 4 + (lane >> 4);
      const int cg = lane & 15;
      float4 q = *(const float4*)&scr[r * 68 + cg * 4];
      uint2 o;
      o.x = pk2bf(q.x, q.y);
      o.y = pk2bf(q.z, q.w);
      *(uint2*)(base + (size_t)(mrow0 + r) * ld + ncol0 + cg * 4) = o;
    }
    asm volatile("s_waitcnt lgkmcnt(0)" ::: "memory");
    __builtin_amdgcn_sched_barrier(0);
  };

  if constexpr (EPI == 4) {
    const int reg = n0 >> 10;  // 0=Q, 1=K, 2=V (block-uniform; N-tiles align)
    const float* bp = (reg == 0) ? bias0 : (reg == 1) ? bias1 : bias2;
    if (reg < 2) {
      u16* base = (u16*)outp + (size_t)reg * (8u * 1024 * 1024);
#pragma unroll
      for (int mt = 0; mt < 8; mt++) {
        float v[4][4];
#pragma unroll
        for (int nt = 0; nt < 4; nt++) {
          const float bs = bp[(n0 + wn + nt * 16 + la) & 1023];
#pragma unroll
          for (int vv = 0; vv < 4; vv++) v[nt][vv] = acc[mt][nt][vv] + bs;
        }
        emit_bf16(base, 1024, m0 + wm + mt * 16, (n0 + wn) & 1023, v);
      }
    } else {
#pragma unroll
      for (int nt = 0; nt < 4; nt++) {
        const int nl = (n0 + wn + nt * 16 + la) & 1023;
        const float bs = bp[nl];
        const int hh = nl >> 6, d = nl & 63;
#pragma unroll
        for (int mt = 0; mt < 8; mt++) {
          const int m = m0 + wm + mt * 16 + lg * 4;
          const int bb2 = m >> 11, s = m & 2047;
          u16* vp = (u16*)outp + 16u * 1024 * 1024 +
                    (((size_t)bb2 * NH + hh) * DK + d) * SS + s;
          uint2 o;
          o.x = pk2bf(acc[mt][nt][0] + bs, acc[mt][nt][1] + bs);
          o.y = pk2bf(acc[mt][nt][2] + bs, acc[mt][nt][3] + bs);
          *(uint2*)vp = o;
        }
      }
    }
  } else {  // EPI == 2: gelu bf16
#pragma unroll
    for (int mt = 0; mt < 8; mt++) {
      float v[4][4];
#pragma unroll
      for (int nt = 0; nt < 4; nt++) {
        const float bs = bias0[n0 + wn + nt * 16 + la];
#pragma unroll
        for (int vv = 0; vv < 4; vv++) {
          const float val = acc[mt][nt][vv] + bs;
          v[nt][vv] = 0.5f * val * (1.f + erff(val * 0.70710678118f));
        }
      }
      emit_bf16((u16*)outp, N, m0 + wm + mt * 16, n0 + wn, v);
    }
  }
#undef PH_BAR_PRE
#undef PH_BAR_POST
}

// ============== r12 GEMM (32x32 MFMA) kept for EPI=1 (N=1024) ==============
template <int EPI>
__global__ __launch_bounds__(512, 4) void k_gemm_bt(const u16* __restrict__ A,
                                                    const u16* __restrict__ BT,
                                                    const float* __restrict__ bias0,
                                                    const float* __restrict__ res,
                                                    void* __restrict__ outp,
                                                    int M, int N, int K) {
  constexpr int ABUF = 256 * 32 * 2;   // 16 KB
  constexpr int BBUF = 128 * 32 * 2;   // 8 KB
  __shared__ char Al[3 * ABUF];
  __shared__ char Bl[3 * BBUF];

  const int tid = threadIdx.x, wave = tid >> 6, lane = tid & 63;
  const int nwg = gridDim.x * gridDim.y;
  const int bid = blockIdx.y * gridDim.x + blockIdx.x;
  const int swz = (bid & 7) * (nwg >> 3) + (bid >> 3);
  const int m0 = (swz / gridDim.x) * 256, n0 = (swz % gridDim.x) * 128;
  const int wm = (wave >> 1) * 64, wn = (wave & 1) * 64;
  const int l31 = lane & 31, l5 = lane >> 5;
  const int psw = (l31 >> 1) & 3;

  fx16 acc[2][2];
#pragma unroll
  for (int i = 0; i < 2; i++)
#pragma unroll
    for (int j = 0; j < 2; j++)
#pragma unroll
      for (int e = 0; e < 16; e++) acc[i][j][e] = 0.f;

  const int arow = tid >> 2;
  const int aslot = ((tid & 3) ^ ((tid >> 3) & 3)) * 8;
  const u16* gA = A  + (size_t)(m0 + arow) * K + aslot;
  const u16* gB = BT + (size_t)(n0 + arow) * K + aslot;

  auto stageAB = [&](int buf, int kt) {
    async16(Al + buf * ABUF + wave * 1024,        gA + kt);
    async16(Al + buf * ABUF + 8192 + wave * 1024, gA + (size_t)128 * K + kt);
    async16(Bl + buf * BBUF + wave * 1024,        gB + kt);
  };

  const int nk = K >> 5;
  stageAB(0, 0);
  stageAB(1, 32);
  asm volatile("s_waitcnt vmcnt(3)" ::: "memory");
  __builtin_amdgcn_sched_barrier(0);
  __builtin_amdgcn_s_barrier();
  asm volatile("" ::: "memory");

  int cur = 0;
  for (int t = 0; t < nk; ++t) {
    const char* Ab = (const char*)Al + cur * ABUF;
    const char* Bb = (const char*)Bl + cur * BBUF;
    bfx8 av[2][2], bv[2][2];
#pragma unroll
    for (int mi = 0; mi < 2; mi++)
#pragma unroll
      for (int kk = 0; kk < 2; kk++)
        av[mi][kk] = *(const bfx8*)(Ab + (wm + mi * 32 + l31) * 64 +
                                    (((kk << 1) | l5) ^ psw) * 16);
#pragma unroll
    for (int ni = 0; ni < 2; ni++)
#pragma unroll
      for (int kk = 0; kk < 2; kk++)
        bv[ni][kk] = *(const bfx8*)(Bb + (wn + ni * 32 + l31) * 64 +
                                    (((kk << 1) | l5) ^ psw) * 16);
    int nb = cur + 2; if (nb >= 3) nb -= 3;
    if (t + 2 < nk) stageAB(nb, (t + 2) << 5);

    __builtin_amdgcn_s_setprio(1);
#pragma unroll
    for (int kk = 0; kk < 2; kk++)
#pragma unroll
      for (int mi = 0; mi < 2; mi++)
#pragma unroll
        for (int ni = 0; ni < 2; ni++)
          acc[mi][ni] = __builtin_amdgcn_mfma_f32_32x32x16_bf16(
              av[mi][kk], bv[ni][kk], acc[mi][ni], 0, 0, 0);
    __builtin_amdgcn_s_setprio(0);

    const int rem = nk - 1 - t;
    if (rem >= 2)      { asm volatile("s_waitcnt vmcnt(3)" ::: "memory"); }
    else if (rem == 1) { asm volatile("s_waitcnt vmcnt(0)" ::: "memory"); }
    __builtin_amdgcn_sched_barrier(0);
    if (rem > 0) __builtin_amdgcn_s_barrier();
    asm volatile("" ::: "memory");
    cur = (cur + 1 == 3) ? 0 : cur + 1;
  }

  // EPI == 1: f32 out + residual (full-sector scalar stores: 32 consecutive n)
#pragma unroll
  for (int ni = 0; ni < 2; ni++) {
    const int n = n0 + wn + ni * 32 + l31;
    const float bs = bias0[n];
#pragma unroll
    for (int mi = 0; mi < 2; mi++) {
#pragma unroll
      for (int r = 0; r < 16; r++) {
        const int row = (r & 3) + 8 * (r >> 2) + 4 * l5;
        const size_t idx = (size_t)(m0 + wm + mi * 32 + row) * N + n;
        ((float*)outp)[idx] = res[idx] + acc[mi][ni][r] + bs;
      }
    }
  }
}

// ---------------- causal flash attention, swapped-QK^T, split-KV ----------
__global__ __launch_bounds__(512, 4) void k_attn(const u16* __restrict__ q,
                                                 const u16* __restrict__ k,
                                                 const u16* __restrict__ vt,
                                                 u16* __restrict__ att) {
  __shared__ char sm[65536];
  const int bid = blockIdx.x;
  const int bq = 15 - (bid >> 6);
  const int bh = bid & 63;
  const int b = bh >> 4, h = bh & 15;

  const int tid = threadIdx.x, wave = tid >> 6, lane = tid & 63;
  const int g = wave >> 2, wv4 = wave & 3;
  const int la = lane & 15, lg = lane >> 4;
  const int q0 = bq * 128;

  bfx8 qf[2][2];
#pragma unroll
  for (int qt = 0; qt < 2; qt++) {
    const u16* qp = q + (size_t)(b * SS + q0 + wv4 * 32 + qt * 16 + la) * DM + h * DK + lg * 8;
#pragma unroll
    for (int f = 0; f < 2; f++) qf[qt][f] = *(const bfx8*)(qp + f * 32);
  }

  fx4 acc[2][4];
#pragma unroll
  for (int qt = 0; qt < 2; qt++)
#pragma unroll
    for (int dt = 0; dt < 4; dt++) acc[qt][dt] = fx4{0.f, 0.f, 0.f, 0.f};
  float mold[2] = {-10000.f, -10000.f};
  float lsum[2] = {0.f, 0.f};

  const int srow = lane >> 3;
  const int sslot = (lane & 7) ^ srow;
  const u16* kg0 = k  + (size_t)(b * SS + wv4 * 16 + srow) * DM + h * DK + sslot * 8;
  const u16* vg0 = vt + (size_t)((b * NH + h) * DK + wv4 * 16 + srow) * SS + sslot * 8;
  char* kbase = sm + g * 32768 + wv4 * 2048;
  char* vbase = sm + g * 32768 + 16384 + wv4 * 2048;

  const float c1 = 0.18033688f;
  const int niter = bq + 1;

  auto stage = [&](int buf, int i) {
    const int c0 = (2 * i + g) * 64;
#pragma unroll
    for (int j = 0; j < 2; j++)
      async16(kbase + buf * 8192 + j * 1024, kg0 + (size_t)(c0 + j * 8) * DM);
#pragma unroll
    for (int j = 0; j < 2; j++)
      async16(vbase + buf * 8192 + j * 1024, vg0 + (size_t)(j * 8) * SS + c0);
  };

  stage(0, 0);
  int cur = 0;
  const int sw = la & 7;

  for (int i = 0; i < niter; i++) {
    __syncthreads();
    if (i + 1 < niter) stage(cur ^ 1, i + 1);
    const int c0 = (2 * i + g) * 64;
    const bool msk = (i == niter - 1);
    const char* Kb = sm + g * 32768 + cur * 8192;
    const char* Vb = sm + g * 32768 + 16384 + cur * 8192;

    fx4 st[2][4];
    __builtin_amdgcn_s_setprio(1);
#pragma unroll
    for (int t = 0; t < 4; t++) {
      const char* kr = Kb + (size_t)(t * 16 + la) * 128;
      bfx8 kf0 = *(const bfx8*)(kr + ((0 + lg) ^ sw) * 16);
      bfx8 kf1 = *(const bfx8*)(kr + ((4 + lg) ^ sw) * 16);
#pragma unroll
      for (int qt = 0; qt < 2; qt++) {
        fx4 z = fx4{0.f, 0.f, 0.f, 0.f};
        z = __builtin_amdgcn_mfma_f32_16x16x32_bf16(kf0, qf[qt][0], z, 0, 0, 0);
        z = __builtin_amdgcn_mfma_f32_16x16x32_bf16(kf1, qf[qt][1], z, 0, 0, 0);
        st[qt][t] = z;
      }
    }
    __builtin_amdgcn_s_setprio(0);

    if (msk) {
#pragma unroll
      for (int qt = 0; qt < 2; qt++) {
        const int qir = q0 + wv4 * 32 + qt * 16 + la;
#pragma unroll
        for (int t = 0; t < 4; t++)
#pragma unroll
          for (int r = 0; r < 4; r++)
            if (c0 + t * 16 + lg * 4 + r > qir) st[qt][t][r] = -1e9f;
      }
    }

    float lmx[2];
#pragma unroll
    for (int qt = 0; qt < 2; qt++) {
      float mx = fmaxf(fmaxf(st[qt][0][0], st[qt][0][1]), fmaxf(st[qt][0][2], st[qt][0][3]));
#pragma unroll
      for (int t = 1; t < 4; t++)
        mx = fmaxf(mx, fmaxf(fmaxf(st[qt][t][0], st[qt][t][1]), fmaxf(st[qt][t][2], st[qt][t][3])));
      lmx[qt] = mx * c1;
    }
    const bool def = (lmx[0] <= mold[0] + 8.f) && (lmx[1] <= mold[1] + 8.f);
    if (!__all(def)) {
#pragma unroll
      for (int qt = 0; qt < 2; qt++) {
        float mx = lmx[qt];
        mx = fmaxf(mx, __shfl_xor(mx, 16));
        mx = fmaxf(mx, __shfl_xor(mx, 32));
        const float mnew  = fmaxf(mold[qt], mx);
        const float scale = exp2f(mold[qt] - mnew);
        mold[qt] = mnew;
        lsum[qt] *= scale;
#pragma unroll
        for (int dt = 0; dt < 4; dt++) {
          acc[qt][dt][0] *= scale; acc[qt][dt][1] *= scale;
          acc[qt][dt][2] *= scale; acc[qt][dt][3] *= scale;
        }
      }
    }
    u32 W[2][4][2];
#pragma unroll
    for (int qt = 0; qt < 2; qt++) {
      float ps = 0.f;
#pragma unroll
      for (int t = 0; t < 4; t++) {
        float p0 = exp2f(fmaf(st[qt][t][0], c1, -mold[qt]));
        float p1 = exp2f(fmaf(st[qt][t][1], c1, -mold[qt]));
        float p2 = exp2f(fmaf(st[qt][t][2], c1, -mold[qt]));
        float p3 = exp2f(fmaf(st[qt][t][3], c1, -mold[qt]));
        ps += (p0 + p1) + (p2 + p3);
        W[qt][t][0] = pk2bf(p0, p1);
        W[qt][t][1] = pk2bf(p2, p3);
      }
      lsum[qt] += ps;
    }

    const int sLo = la + ((lg & 1) << 5);
    const int sHi = sLo + 16;
    const bool tHi = (lg >> 1) & 1;
#pragma unroll
    for (int f = 0; f < 2; f++) {
      bfx8 pf[2];
#pragma unroll
      for (int qt = 0; qt < 2; qt++) {
        const u32 a0 = __shfl(W[qt][2 * f][0], sLo), b0 = __shfl(W[qt][2 * f + 1][0], sLo);
        const u32 a1 = __shfl(W[qt][2 * f][1], sLo), b1 = __shfl(W[qt][2 * f + 1][1], sLo);
        const u32 a2 = __shfl(W[qt][2 * f][0], sHi), b2 = __shfl(W[qt][2 * f + 1][0], sHi);
        const u32 a3 = __shfl(W[qt][2 * f][1], sHi), b3 = __shfl(W[qt][2 * f + 1][1], sHi);
        union { u32 u[4]; bfx8 v; } pu;
        pu.u[0] = tHi ? b0 : a0;
        pu.u[1] = tHi ? b1 : a1;
        pu.u[2] = tHi ? b2 : a2;
        pu.u[3] = tHi ? b3 : a3;
        pf[qt] = pu.v;
      }
      __builtin_amdgcn_s_setprio(1);
#pragma unroll
      for (int dt = 0; dt < 4; dt++) {
        const int row = dt * 16 + la;
        bfx8 vf = *(const bfx8*)(Vb + (size_t)row * 128 + (((f << 2) + lg) ^ sw) * 16);
        acc[0][dt] = __builtin_amdgcn_mfma_f32_16x16x32_bf16(vf, pf[0], acc[0][dt], 0, 0, 0);
        acc[1][dt] = __builtin_amdgcn_mfma_f32_16x16x32_bf16(vf, pf[1], acc[1][dt], 0, 0, 0);
      }
      __builtin_amdgcn_s_setprio(0);
    }
    cur ^= 1;
  }

#pragma unroll
  for (int qt = 0; qt < 2; qt++) {
    lsum[qt] += __shfl_xor(lsum[qt], 16);
    lsum[qt] += __shfl_xor(lsum[qt], 32);
  }

  __syncthreads();
  const int gi = wv4 * 64 + lane;
  float* scr = (float*)sm + (size_t)gi * 36;
  if (g == 1) {
#pragma unroll
    for (int qt = 0; qt < 2; qt++)
#pragma unroll
      for (int dt = 0; dt < 4; dt++)
#pragma unroll
        for (int j = 0; j < 4; j++) scr[qt * 16 + dt * 4 + j] = acc[qt][dt][j];
    scr[32] = mold[0]; scr[33] = mold[1];
    scr[34] = lsum[0]; scr[35] = lsum[1];
  }
  __syncthreads();
  if (g == 0) {
#pragma unroll
    for (int qt = 0; qt < 2; qt++) {
      const float mB = scr[32 + qt], lB = scr[34 + qt];
      const float mN = fmaxf(mold[qt], mB);
      const float sA = exp2f(mold[qt] - mN);
      const float sB = exp2f(mB - mN);
      const float inv = 1.f / (lsum[qt] * sA + lB * sB);
      u16* ob = att + (size_t)(b * SS + q0 + wv4 * 32 + qt * 16 + la) * DM + h * DK + lg * 4;
#pragma unroll
      for (int dt = 0; dt < 4; dt++) {
        float o0 = (acc[qt][dt][0] * sA + scr[qt * 16 + dt * 4 + 0] * sB) * inv;
        float o1 = (acc[qt][dt][1] * sA + scr[qt * 16 + dt * 4 + 1] * sB) * inv;
        float o2 = (acc[qt][dt][2] * sA + scr[qt * 16 + dt * 4 + 2] * sB) * inv;
        float o3 = (acc[qt][dt][3] * sA + scr[qt * 16 + dt * 4 + 3] * sB) * inv;
        uint2 o;
        o.x = pk2bf(o0, o1);
        o.y = pk2bf(o2, o3);
        *(uint2*)(ob + dt * 16) = o;
      }
    }
  }
}

// ---------------------------------------------------------------------------
extern "C" void kernel_launch(void* const* d_in, const int* in_sizes, int n_in,
                              void* d_out, int out_size, void* d_ws, size_t ws_size,
                              hipStream_t stream) {
  const float* x    = (const float*)d_in[0];
  const float* wq   = (const float*)d_in[1];
  const float* bq   = (const float*)d_in[2];
  const float* wk   = (const float*)d_in[3];
  const float* bk   = (const float*)d_in[4];
  const float* wv   = (const float*)d_in[5];
  const float* bv   = (const float*)d_in[6];
  const float* wo   = (const float*)d_in[7];
  const float* bo   = (const float*)d_in[8];
  const float* w1   = (const float*)d_in[9];
  const float* b1   = (const float*)d_in[10];
  const float* w2   = (const float*)d_in[11];
  const float* b2   = (const float*)d_in[12];
  const float* ln1g = (const float*)d_in[13];
  const float* ln1b = (const float*)d_in[14];
  const float* ln2g = (const float*)d_in[15];
  const float* ln2b = (const float*)d_in[16];
  float* out = (float*)d_out;

  char* w = (char*)d_ws;
  const size_t MB = 1024ull * 1024ull;
  u16*   wqkv = (u16*)(w + 0 * MB);   // [3072][1024] bf16 (Q,K,V stacked)
  u16*   wot  = (u16*)(w + 6 * MB);   // [1024][1024]
  u16*   w1t  = (u16*)(w + 8 * MB);   // [4096][1024]
  u16*   w2t  = (u16*)(w + 16 * MB);  // [1024][4096]
  float* x2   = (float*)(w + 24 * MB);// [8192][1024] f32
  u16*   hb   = (u16*)(w + 56 * MB);  // [8192][1024] (h, then h2)
  u16*   qb   = (u16*)(w + 72 * MB);  // [8192][1024]; K at +8M u16, V^T at +16M u16
  u16*   kb   = (u16*)(w + 88 * MB);
  u16*   vtb  = (u16*)(w + 104 * MB); // [4][16][64][2048] V^T per head
  u16*   atb  = (u16*)(w + 120 * MB); // [8192][1024]
  u16*   ffb  = (u16*)(w + 72 * MB);  // [8192][4096] overlays q/k/vt/att

  // 1) ALL weight transposes in one launch (f32 -> bf16 W^T)
  k_transpose_all<<<dim3(12288), 256, 0, stream>>>(wq, wk, wv, wo, w1, w2,
                                                   wqkv, wot, w1t, w2t);

  // 2) LN1: x -> h (bf16)
  k_layernorm<<<MROWS / 4, 256, 0, stream>>>(x, ln1g, ln1b, hb);

  // 3) fused QKV projection: 256x256 template -> 12x32 = 384 blocks
  k_gemm256<4><<<dim3(12, 32), 512, 0, stream>>>(hb, wqkv, bq, bk, bv, qb,
                                                 MROWS, 3 * DM, DM);

  // 4) causal flash attention (swapped QK^T, split-KV, 8 waves)
  k_attn<<<dim3(1024), 512, 0, stream>>>(qb, kb, vtb, atb);

  // 5) O projection + residual (f32 x2): 8x32 = 256 blocks
  k_gemm_bt<1><<<dim3(8, 32), 512, 0, stream>>>(atb, wot, bo, x, x2,
                                                MROWS, DM, DM);

  // 6) LN2: x2 -> h2 (bf16, reuse hb)
  k_layernorm<<<MROWS / 4, 256, 0, stream>>>(x2, ln2g, ln2b, hb);

  // 7) FF1 + GELU: 256x256 template -> 16x32 = 512 blocks
  k_gemm256<2><<<dim3(16, 32), 512, 0, stream>>>(hb, w1t, b1, nullptr, nullptr, ffb,
                                                 MROWS, DFF, DM);

  // 8) FF2 + residual -> d_out (f32): 8x32 = 256 blocks
  k_gemm_bt<1><<<dim3(8, 32), 512, 0, stream>>>(ffb, w2t, b2, x2, out,
                                                MROWS, DM, DFF);
}

// Round 14
// 388.051 us; speedup vs baseline: 1.6231x; 1.1109x over previous
//
#include <hip/hip_runtime.h>
#include <hip/hip_bf16.h>

#define DM   1024
#define DFF  4096
#define NB   4
#define SS   2048
#define NH   16
#define DK   64
#define MROWS (NB*SS)   // 8192

typedef __attribute__((ext_vector_type(8))) short bfx8;
typedef __attribute__((ext_vector_type(4))) float fx4;
typedef unsigned int u32;
typedef unsigned short u16;

static __device__ __forceinline__ u16 f2bf(float f) {
  union { __hip_bfloat16 h; u16 u; } cv;
  cv.h = __float2bfloat16(f);
  return cv.u;
}
static __device__ __forceinline__ u32 pk2bf(float a, float b) {
  return (u32)f2bf(a) | ((u32)f2bf(b) << 16);
}

static __device__ __forceinline__ void async16(void* lds, const void* g) {
  typedef const __attribute__((address_space(1))) unsigned int* gp_t;
  typedef __attribute__((address_space(3))) unsigned int* lp_t;
  __builtin_amdgcn_global_load_lds((gp_t)g, (lp_t)lds, 16, 0, 0);
}

// ------------- ALL weight transposes in one launch: out[n][k] = in[k][n] ----
__global__ __launch_bounds__(256) void k_transpose_all(
    const float* __restrict__ wq, const float* __restrict__ wk,
    const float* __restrict__ wv, const float* __restrict__ wo,
    const float* __restrict__ w1, const float* __restrict__ w2,
    u16* __restrict__ wqkv, u16* __restrict__ wot,
    u16* __restrict__ w1t,  u16* __restrict__ w2t) {
  __shared__ float t[32][33];
  const int idx = blockIdx.x;
  const float* in; u16* out; int K, N, bx, by;
  if (idx < 4096) {
    const int m = idx >> 10, tl = idx & 1023;
    in  = (m == 0) ? wq : (m == 1) ? wk : (m == 2) ? wv : wo;
    out = (m < 3) ? (wqkv + (size_t)m * 1024 * 1024) : wot;
    K = 1024; N = 1024; bx = tl & 31; by = tl >> 5;
  } else if (idx < 8192) {
    const int tl = idx - 4096;
    in = w1; out = w1t; K = 1024; N = 4096; bx = tl & 127; by = tl >> 7;
  } else {
    const int tl = idx - 8192;
    in = w2; out = w2t; K = 4096; N = 1024; bx = tl & 31; by = tl >> 5;
  }
  const int n0 = bx * 32, k0 = by * 32;
  const int tx = threadIdx.x & 31, ty = threadIdx.x >> 5;  // 32 x 8
#pragma unroll
  for (int j = 0; j < 4; j++)
    t[ty + j * 8][tx] = in[(size_t)(k0 + ty + j * 8) * N + n0 + tx];
  __syncthreads();
#pragma unroll
  for (int j = 0; j < 4; j++)
    out[(size_t)(n0 + ty + j * 8) * K + k0 + tx] = f2bf(t[tx][ty + j * 8]);
}

// ---------------- layernorm: f32 in -> bf16 out, one wave per row ----------
__global__ __launch_bounds__(256) void k_layernorm(const float* __restrict__ x,
                                                   const float* __restrict__ g,
                                                   const float* __restrict__ b,
                                                   u16* __restrict__ out) {
  const int row  = blockIdx.x * 4 + (threadIdx.x >> 6);
  const int lane = threadIdx.x & 63;
  const float* xr = x + (size_t)row * DM;
  float4 vb[4];
  float s = 0.f, s2 = 0.f;
#pragma unroll
  for (int j = 0; j < 4; j++) {
    float4 v = *(const float4*)(xr + j * 256 + lane * 4);
    vb[j] = v;
    s  += v.x + v.y + v.z + v.w;
    s2 += v.x * v.x + v.y * v.y + v.z * v.z + v.w * v.w;
  }
#pragma unroll
  for (int off = 1; off < 64; off <<= 1) {
    s  += __shfl_xor(s,  off);
    s2 += __shfl_xor(s2, off);
  }
  const float mu   = s * (1.f / DM);
  const float var  = s2 * (1.f / DM) - mu * mu;
  const float rstd = rsqrtf(var + 1e-5f);
  u16* orow = out + (size_t)row * DM;
#pragma unroll
  for (int j = 0; j < 4; j++) {
    const int col = j * 256 + lane * 4;
    uint2 o;
    o.x = pk2bf((vb[j].x - mu) * rstd * g[col + 0] + b[col + 0],
                (vb[j].y - mu) * rstd * g[col + 1] + b[col + 1]);
    o.y = pk2bf((vb[j].z - mu) * rstd * g[col + 2] + b[col + 2],
                (vb[j].w - mu) * rstd * g[col + 3] + b[col + 3]);
    *(uint2*)(orow + col) = o;
  }
}

// ---------------- GEMM (r10, proven 403us base): ring-4, counted vmcnt -----
// BM=256, 8 waves (512 thr), NWR=4: BN=128, wave tile 64x64 (4x4 16x16 frags)
// BK=32, 64B LDS rows, XOR swizzle slot^((row>>1)&3), one barrier per K-tile.
// bf16 epilogues bounce via LDS for full-sector stores.
// EPI: 1 = f32 out (+res), 4 = fused QKV (Q,K row-major; V per-head-T)
template <int EPI, int NWR>
__global__ __launch_bounds__(512, 2) void k_gemm_bt(const u16* __restrict__ A,
                                                    const u16* __restrict__ BT,
                                                    const float* __restrict__ bias0,
                                                    const float* __restrict__ bias1,
                                                    const float* __restrict__ bias2,
                                                    const float* __restrict__ res,
                                                    void* __restrict__ outp,
                                                    int M, int N, int K) {
  constexpr int NWC   = 8 / NWR;
  constexpr int BN    = NWC * 64;            // 128 for NWR=4
  constexpr int MFRAG = 256 / NWR / 16;      // 4
  constexpr int ABUF  = 256 * 32 * 2;        // 16 KB per K-tile buffer
  constexpr int BBUF  = BN * 32 * 2;         // 8 KB
  constexpr int SA    = 2;
  constexpr int SB    = BBUF / 8192;         // 1
  constexpr int S     = SA + SB;             // 3

  __shared__ char Al[4 * ABUF];              // 64 KB (reused as epilogue bounce)
  __shared__ char Bl[4 * BBUF];              // 32 KB

  const int tid = threadIdx.x, wave = tid >> 6, lane = tid & 63;
  const int nwg = gridDim.x * gridDim.y;
  const int bid = blockIdx.y * gridDim.x + blockIdx.x;
  const int swz = (bid & 7) * (nwg >> 3) + (bid >> 3);
  const int m0 = (swz / gridDim.x) * 256, n0 = (swz % gridDim.x) * BN;
  const int wr = wave / NWC, wc = wave % NWC;
  const int wm = wr * (256 / NWR), wn = wc * 64;
  const int la = lane & 15, lg = lane >> 4;
  const int psw = (la >> 1) & 3;

  fx4 acc[MFRAG][4];
#pragma unroll
  for (int i = 0; i < MFRAG; i++)
#pragma unroll
    for (int j = 0; j < 4; j++) acc[i][j] = fx4{0.f, 0.f, 0.f, 0.f};

  const int arow = tid >> 2;
  const int aslot = ((tid & 3) ^ ((tid >> 3) & 3)) * 8;
  const u16* gA = A  + (size_t)(m0 + arow) * K + aslot;
  const u16* gB = BT + (size_t)(n0 + arow) * K + aslot;

  auto stageA = [&](int buf, int kt) {
#pragma unroll
    for (int j = 0; j < SA; j++)
      async16(Al + buf * ABUF + j * 8192 + wave * 1024, gA + (size_t)(j * 128) * K + kt);
  };
  auto stageB = [&](int buf, int kt) {
#pragma unroll
    for (int j = 0; j < SB; j++)
      async16(Bl + buf * BBUF + j * 8192 + wave * 1024, gB + (size_t)(j * 128) * K + kt);
  };

  const int nk = K >> 5;
  stageA(0, 0);  stageB(0, 0);
  stageA(1, 32); stageB(1, 32);
  stageA(2, 64); stageB(2, 64);
  asm volatile("s_waitcnt vmcnt(%0)" :: "n"(2 * S) : "memory");
  __builtin_amdgcn_s_barrier();
  asm volatile("" ::: "memory");

  for (int t = 0; t < nk; ++t) {
    const char* Ab = (const char*)Al + (t & 3) * ABUF;
    const char* Bb = (const char*)Bl + (t & 3) * BBUF;
    const int rem = nk - 1 - t;
    const bool pf = (t + 3 < nk);
    const int pb = (t + 3) & 3;
    const int pk = (t + 3) << 5;

    bfx8 av[MFRAG], bv[4];
#pragma unroll
    for (int i = 0; i < MFRAG; i++)
      av[i] = *(const bfx8*)(Ab + (wm + i * 16 + la) * 64 + (lg ^ psw) * 16);
#pragma unroll
    for (int i = 0; i < 4; i++)
      bv[i] = *(const bfx8*)(Bb + (wn + i * 16 + la) * 64 + (lg ^ psw) * 16);
    if (pf) { stageA(pb, pk); stageB(pb, pk); }
    asm volatile("" ::: "memory");
    __builtin_amdgcn_s_barrier();
    asm volatile("" ::: "memory");
    __builtin_amdgcn_s_setprio(1);
#pragma unroll
    for (int mt = 0; mt < MFRAG; mt++)
#pragma unroll
      for (int nt = 0; nt < 4; nt++)
        acc[mt][nt] = __builtin_amdgcn_mfma_f32_16x16x32_bf16(av[mt], bv[nt], acc[mt][nt], 0, 0, 0);
    __builtin_amdgcn_s_setprio(0);
    if (rem >= 3)      { asm volatile("s_waitcnt vmcnt(%0)" :: "n"(2 * S) : "memory"); }
    else if (rem == 2) { asm volatile("s_waitcnt vmcnt(%0)" :: "n"(S)     : "memory"); }
    else if (rem == 1) { asm volatile("s_waitcnt vmcnt(0)" ::: "memory"); }
    asm volatile("" ::: "memory");
    __builtin_amdgcn_s_barrier();
    asm volatile("" ::: "memory");
  }

  // ============ epilogue ============
  float* scr = (float*)(void*)Al + (size_t)wave * (68 * 16);

  auto emit_bf16 = [&](u16* base, size_t ld, int mrow0, int ncol0,
                       const float v[4][4]) {
#pragma unroll
    for (int nt = 0; nt < 4; nt++)
#pragma unroll
      for (int vv = 0; vv < 4; vv++)
        scr[(lg * 4 + vv) * 68 + nt * 16 + la] = v[nt][vv];
    asm volatile("s_waitcnt lgkmcnt(0)" ::: "memory");
#pragma unroll
    for (int p = 0; p < 4; p++) {
      const int r  = p * 4 + (lane >> 4);
      const int cg = lane & 15;
      float4 q = *(const float4*)&scr[r * 68 + cg * 4];
      uint2 o;
      o.x = pk2bf(q.x, q.y);
      o.y = pk2bf(q.z, q.w);
      *(uint2*)(base + (size_t)(mrow0 + r) * ld + ncol0 + cg * 4) = o;
    }
    asm volatile("s_waitcnt lgkmcnt(0)" ::: "memory");
  };

  if constexpr (EPI == 4) {
    const int reg = n0 >> 10;  // 0=Q, 1=K, 2=V
    const float* bp = (reg == 0) ? bias0 : (reg == 1) ? bias1 : bias2;
    if (reg < 2) {
      u16* base = (u16*)outp + (size_t)reg * (8u * 1024 * 1024);
#pragma unroll
      for (int mt = 0; mt < MFRAG; mt++) {
        float v[4][4];
#pragma unroll
        for (int nt = 0; nt < 4; nt++) {
          const float bs = bp[(n0 + wn + nt * 16 + la) & 1023];
#pragma unroll
          for (int vv = 0; vv < 4; vv++) v[nt][vv] = acc[mt][nt][vv] + bs;
        }
        emit_bf16(base, 1024, m0 + wm + mt * 16, (n0 + wn) & 1023, v);
      }
    } else {
#pragma unroll
      for (int nt = 0; nt < 4; nt++) {
        const int nl = (n0 + wn + nt * 16 + la) & 1023;
        const float bs = bp[nl];
        const int hh = nl >> 6, d = nl & 63;
#pragma unroll
        for (int mt = 0; mt < MFRAG; mt++) {
          const int m = m0 + wm + mt * 16 + lg * 4;
          const int bb2 = m >> 11, s = m & 2047;
          u16* vp = (u16*)outp + 16u * 1024 * 1024 +
                    (((size_t)bb2 * NH + hh) * DK + d) * SS + s;
          uint2 o;
          o.x = pk2bf(acc[mt][nt][0] + bs, acc[mt][nt][1] + bs);
          o.y = pk2bf(acc[mt][nt][2] + bs, acc[mt][nt][3] + bs);
          *(uint2*)vp = o;
        }
      }
    }
  } else {  // EPI == 1: f32 out + residual
#pragma unroll
    for (int nt = 0; nt < 4; nt++) {
      const int n = n0 + wn + nt * 16 + la;
      const float bs = bias0[n];
#pragma unroll
      for (int mt = 0; mt < MFRAG; mt++) {
#pragma unroll
        for (int vv = 0; vv < 4; vv++) {
          const int m = m0 + wm + mt * 16 + lg * 4 + vv;
          const size_t idx = (size_t)m * N + n;
          ((float*)outp)[idx] = res[idx] + acc[mt][nt][vv] + bs;
        }
      }
    }
  }
}

// ======================= m201-template GEMM (FF1 gelu) =====================
// (r13, proven correct; FF1 <= 109us there.) 256x256 tile, 8 waves (2Mx4N),
// wave tile 128x64, BK=64, double-buffered 128KB LDS, 4 phases per K-tile,
// counted vmcnt(4) at phases 1/3.
__global__ __launch_bounds__(512, 2) void k_gemm256_gelu(const u16* __restrict__ A,
                                                         const u16* __restrict__ BT,
                                                         const float* __restrict__ bias0,
                                                         void* __restrict__ outp,
                                                         int M, int N, int K) {
  __shared__ char Sl[131072];

  const int tid = threadIdx.x, wave = tid >> 6, lane = tid & 63;
  const int nwg = gridDim.x * gridDim.y;
  const int bid = blockIdx.y * gridDim.x + blockIdx.x;
  const int swz = (bid & 7) * (nwg >> 3) + (bid >> 3);
  const int m0 = (swz / gridDim.x) * 256, n0 = (swz % gridDim.x) * 256;
  const int wr = wave >> 2, wcn = wave & 3;
  const int la = lane & 15, lg = lane >> 4;
  const int psw = (la >> 1) & 3;

  fx4 acc[8][4];
#pragma unroll
  for (int i = 0; i < 8; i++)
#pragma unroll
    for (int j = 0; j < 4; j++) acc[i][j] = fx4{0.f, 0.f, 0.f, 0.f};

  const int rp  = wave * 16 + (lane >> 2);
  const int sl  = (lane & 3) ^ ((lane >> 3) & 3);
  const int gra = (rp >> 6) * 128 + (rp & 63);
  const int grb = (rp >> 5) * 64 + (rp & 31);

  auto stageA = [&](int buf, int mh, int kt) {
    const u16* src = A + (size_t)(m0 + gra + mh * 64) * K + kt + sl * 8;
    char* dst = Sl + buf * 32768 + mh * 16384 + wave * 1024;
    async16(dst,        src);
    async16(dst + 8192, src + 32);
  };
  auto stageB = [&](int buf, int nh, int kt) {
    const u16* src = BT + (size_t)(n0 + grb + nh * 32) * K + kt + sl * 8;
    char* dst = Sl + 65536 + buf * 32768 + nh * 16384 + wave * 1024;
    async16(dst,        src);
    async16(dst + 8192, src + 32);
  };

  const int nk = K >> 6;
  stageA(0, 0, 0); stageB(0, 0, 0); stageA(0, 1, 0); stageB(0, 1, 0);
  asm volatile("s_waitcnt vmcnt(4)" ::: "memory");
  __builtin_amdgcn_sched_barrier(0);
  __builtin_amdgcn_s_barrier();
  asm volatile("" ::: "memory");

  bfx8 avv[4][2], bv0[2][2], bv1[2][2];

  auto readA = [&](int buf, int mh) {
    const char* base = Sl + buf * 32768 + mh * 16384;
#pragma unroll
    for (int mtl = 0; mtl < 4; mtl++) {
      const int r = wr * 64 + mtl * 16 + la;
#pragma unroll
      for (int kk = 0; kk < 2; kk++)
        avv[mtl][kk] = *(const bfx8*)(base + kk * 8192 + r * 64 + ((lg ^ psw) * 16));
    }
  };
  auto readB = [&](int buf, int nh, bfx8 (&bv)[2][2]) {
    const char* base = Sl + 65536 + buf * 32768 + nh * 16384;
#pragma unroll
    for (int ntl = 0; ntl < 2; ntl++) {
      const int r = wcn * 32 + ntl * 16 + la;
#pragma unroll
      for (int kk = 0; kk < 2; kk++)
        bv[ntl][kk] = *(const bfx8*)(base + kk * 8192 + r * 64 + ((lg ^ psw) * 16));
    }
  };
  auto quad = [&](int mh, int nh, bfx8 (&bv)[2][2]) {
    __builtin_amdgcn_s_setprio(1);
#pragma unroll
    for (int kk = 0; kk < 2; kk++)
#pragma unroll
      for (int mtl = 0; mtl < 4; mtl++)
#pragma unroll
        for (int ntl = 0; ntl < 2; ntl++)
          acc[mh * 4 + mtl][nh * 2 + ntl] = __builtin_amdgcn_mfma_f32_16x16x32_bf16(
              avv[mtl][kk], bv[ntl][kk], acc[mh * 4 + mtl][nh * 2 + ntl], 0, 0, 0);
    __builtin_amdgcn_s_setprio(0);
  };

#define PH_BAR_PRE()  do { __builtin_amdgcn_sched_barrier(0); __builtin_amdgcn_s_barrier(); \
                           asm volatile("s_waitcnt lgkmcnt(0)" ::: "memory");                \
                           __builtin_amdgcn_sched_barrier(0); } while (0)
#define PH_BAR_POST() do { __builtin_amdgcn_sched_barrier(0); __builtin_amdgcn_s_barrier(); \
                           asm volatile("" ::: "memory"); } while (0)

#pragma unroll 1
  for (int t = 0; t < nk; ++t) {
    const int buf = t & 1, nbuf = buf ^ 1;
    const bool pf = (t + 1 < nk);
    const int nkt = (t + 1) << 6;
    readA(buf, 0);
    readB(buf, 0, bv0);
    if (pf) stageA(nbuf, 0, nkt);
    PH_BAR_PRE();
    quad(0, 0, bv0);
    PH_BAR_POST();
    readB(buf, 1, bv1);
    if (pf) stageB(nbuf, 0, nkt);
    if (pf) { asm volatile("s_waitcnt vmcnt(4)" ::: "memory"); }
    else    { asm volatile("s_waitcnt vmcnt(0)" ::: "memory"); }
    PH_BAR_PRE();
    quad(0, 1, bv1);
    PH_BAR_POST();
    readA(buf, 1);
    if (pf) stageA(nbuf, 1, nkt);
    PH_BAR_PRE();
    quad(1, 0, bv0);
    PH_BAR_POST();
    if (pf) {
      stageB(nbuf, 1, nkt);
      asm volatile("s_waitcnt vmcnt(4)" ::: "memory");
    }
    PH_BAR_PRE();
    quad(1, 1, bv1);
    PH_BAR_POST();
  }
  __syncthreads();

  // ---- epilogue: gelu -> bf16 via LDS bounce (full-sector stores) ----
  const int wm = wr * 128, wn = wcn * 64;
  float* scr = (float*)(void*)Sl + (size_t)wave * (68 * 16);

#pragma unroll
  for (int mt = 0; mt < 8; mt++) {
    float v[4][4];
#pragma unroll
    for (int nt = 0; nt < 4; nt++) {
      const float bs = bias0[n0 + wn + nt * 16 + la];
#pragma unroll
      for (int vv = 0; vv < 4; vv++) {
        const float val = acc[mt][nt][vv] + bs;
        v[nt][vv] = 0.5f * val * (1.f + erff(val * 0.70710678118f));
      }
    }
#pragma unroll
    for (int nt = 0; nt < 4; nt++)
#pragma unroll
      for (int vv = 0; vv < 4; vv++)
        scr[(lg * 4 + vv) * 68 + nt * 16 + la] = v[nt][vv];
    asm volatile("s_waitcnt lgkmcnt(0)" ::: "memory");
    __builtin_amdgcn_sched_barrier(0);
#pragma unroll
    for (int p = 0; p < 4; p++) {
      const int r  = p * 4 + (lane >> 4);
      const int cg = lane & 15;
      float4 q = *(const float4*)&scr[r * 68 + cg * 4];
      uint2 o;
      o.x = pk2bf(q.x, q.y);
      o.y = pk2bf(q.z, q.w);
      *(uint2*)((u16*)outp + (size_t)(m0 + wm + mt * 16 + r) * N + n0 + wn + cg * 4) = o;
    }
    asm volatile("s_waitcnt lgkmcnt(0)" ::: "memory");
    __builtin_amdgcn_sched_barrier(0);
  }
#undef PH_BAR_PRE
#undef PH_BAR_POST
}

// ---------------- causal flash attention, swapped-QK^T, split-KV ----------
// (unchanged from r10 -- proven)
__global__ __launch_bounds__(512, 4) void k_attn(const u16* __restrict__ q,
                                                 const u16* __restrict__ k,
                                                 const u16* __restrict__ vt,
                                                 u16* __restrict__ att) {
  __shared__ char sm[65536];
  const int bid = blockIdx.x;
  const int bq = 15 - (bid >> 6);
  const int bh = bid & 63;
  const int b = bh >> 4, h = bh & 15;

  const int tid = threadIdx.x, wave = tid >> 6, lane = tid & 63;
  const int g = wave >> 2, wv4 = wave & 3;
  const int la = lane & 15, lg = lane >> 4;
  const int q0 = bq * 128;

  bfx8 qf[2][2];
#pragma unroll
  for (int qt = 0; qt < 2; qt++) {
    const u16* qp = q + (size_t)(b * SS + q0 + wv4 * 32 + qt * 16 + la) * DM + h * DK + lg * 8;
#pragma unroll
    for (int f = 0; f < 2; f++) qf[qt][f] = *(const bfx8*)(qp + f * 32);
  }

  fx4 acc[2][4];
#pragma unroll
  for (int qt = 0; qt < 2; qt++)
#pragma unroll
    for (int dt = 0; dt < 4; dt++) acc[qt][dt] = fx4{0.f, 0.f, 0.f, 0.f};
  float mold[2] = {-10000.f, -10000.f};
  float lsum[2] = {0.f, 0.f};

  const int srow = lane >> 3;
  const int sslot = (lane & 7) ^ srow;
  const u16* kg0 = k  + (size_t)(b * SS + wv4 * 16 + srow) * DM + h * DK + sslot * 8;
  const u16* vg0 = vt + (size_t)((b * NH + h) * DK + wv4 * 16 + srow) * SS + sslot * 8;
  char* kbase = sm + g * 32768 + wv4 * 2048;
  char* vbase = sm + g * 32768 + 16384 + wv4 * 2048;

  const float c1 = 0.18033688f;
  const int niter = bq + 1;

  auto stage = [&](int buf, int i) {
    const int c0 = (2 * i + g) * 64;
#pragma unroll
    for (int j = 0; j < 2; j++)
      async16(kbase + buf * 8192 + j * 1024, kg0 + (size_t)(c0 + j * 8) * DM);
#pragma unroll
    for (int j = 0; j < 2; j++)
      async16(vbase + buf * 8192 + j * 1024, vg0 + (size_t)(j * 8) * SS + c0);
  };

  stage(0, 0);
  int cur = 0;
  const int sw = la & 7;

  for (int i = 0; i < niter; i++) {
    __syncthreads();
    if (i + 1 < niter) stage(cur ^ 1, i + 1);
    const int c0 = (2 * i + g) * 64;
    const bool msk = (i == niter - 1);
    const char* Kb = sm + g * 32768 + cur * 8192;
    const char* Vb = sm + g * 32768 + 16384 + cur * 8192;

    fx4 st[2][4];
    __builtin_amdgcn_s_setprio(1);
#pragma unroll
    for (int t = 0; t < 4; t++) {
      const char* kr = Kb + (size_t)(t * 16 + la) * 128;
      bfx8 kf0 = *(const bfx8*)(kr + ((0 + lg) ^ sw) * 16);
      bfx8 kf1 = *(const bfx8*)(kr + ((4 + lg) ^ sw) * 16);
#pragma unroll
      for (int qt = 0; qt < 2; qt++) {
        fx4 z = fx4{0.f, 0.f, 0.f, 0.f};
        z = __builtin_amdgcn_mfma_f32_16x16x32_bf16(kf0, qf[qt][0], z, 0, 0, 0);
        z = __builtin_amdgcn_mfma_f32_16x16x32_bf16(kf1, qf[qt][1], z, 0, 0, 0);
        st[qt][t] = z;
      }
    }
    __builtin_amdgcn_s_setprio(0);

    if (msk) {
#pragma unroll
      for (int qt = 0; qt < 2; qt++) {
        const int qir = q0 + wv4 * 32 + qt * 16 + la;
#pragma unroll
        for (int t = 0; t < 4; t++)
#pragma unroll
          for (int r = 0; r < 4; r++)
            if (c0 + t * 16 + lg * 4 + r > qir) st[qt][t][r] = -1e9f;
      }
    }

    float lmx[2];
#pragma unroll
    for (int qt = 0; qt < 2; qt++) {
      float mx = fmaxf(fmaxf(st[qt][0][0], st[qt][0][1]), fmaxf(st[qt][0][2], st[qt][0][3]));
#pragma unroll
      for (int t = 1; t < 4; t++)
        mx = fmaxf(mx, fmaxf(fmaxf(st[qt][t][0], st[qt][t][1]), fmaxf(st[qt][t][2], st[qt][t][3])));
      lmx[qt] = mx * c1;
    }
    const bool def = (lmx[0] <= mold[0] + 8.f) && (lmx[1] <= mold[1] + 8.f);
    if (!__all(def)) {
#pragma unroll
      for (int qt = 0; qt < 2; qt++) {
        float mx = lmx[qt];
        mx = fmaxf(mx, __shfl_xor(mx, 16));
        mx = fmaxf(mx, __shfl_xor(mx, 32));
        const float mnew  = fmaxf(mold[qt], mx);
        const float scale = exp2f(mold[qt] - mnew);
        mold[qt] = mnew;
        lsum[qt] *= scale;
#pragma unroll
        for (int dt = 0; dt < 4; dt++) {
          acc[qt][dt][0] *= scale; acc[qt][dt][1] *= scale;
          acc[qt][dt][2] *= scale; acc[qt][dt][3] *= scale;
        }
      }
    }
    u32 W[2][4][2];
#pragma unroll
    for (int qt = 0; qt < 2; qt++) {
      float ps = 0.f;
#pragma unroll
      for (int t = 0; t < 4; t++) {
        float p0 = exp2f(fmaf(st[qt][t][0], c1, -mold[qt]));
        float p1 = exp2f(fmaf(st[qt][t][1], c1, -mold[qt]));
        float p2 = exp2f(fmaf(st[qt][t][2], c1, -mold[qt]));
        float p3 = exp2f(fmaf(st[qt][t][3], c1, -mold[qt]));
        ps += (p0 + p1) + (p2 + p3);
        W[qt][t][0] = pk2bf(p0, p1);
        W[qt][t][1] = pk2bf(p2, p3);
      }
      lsum[qt] += ps;
    }

    const int sLo = la + ((lg & 1) << 5);
    const int sHi = sLo + 16;
    const bool tHi = (lg >> 1) & 1;
#pragma unroll
    for (int f = 0; f < 2; f++) {
      bfx8 pf[2];
#pragma unroll
      for (int qt = 0; qt < 2; qt++) {
        const u32 a0 = __shfl(W[qt][2 * f][0], sLo), b0 = __shfl(W[qt][2 * f + 1][0], sLo);
        const u32 a1 = __shfl(W[qt][2 * f][1], sLo), b1 = __shfl(W[qt][2 * f + 1][1], sLo);
        const u32 a2 = __shfl(W[qt][2 * f][0], sHi), b2 = __shfl(W[qt][2 * f + 1][0], sHi);
        const u32 a3 = __shfl(W[qt][2 * f][1], sHi), b3 = __shfl(W[qt][2 * f + 1][1], sHi);
        union { u32 u[4]; bfx8 v; } pu;
        pu.u[0] = tHi ? b0 : a0;
        pu.u[1] = tHi ? b1 : a1;
        pu.u[2] = tHi ? b2 : a2;
        pu.u[3] = tHi ? b3 : a3;
        pf[qt] = pu.v;
      }
      __builtin_amdgcn_s_setprio(1);
#pragma unroll
      for (int dt = 0; dt < 4; dt++) {
        const int row = dt * 16 + la;
        bfx8 vf = *(const bfx8*)(Vb + (size_t)row * 128 + (((f << 2) + lg) ^ sw) * 16);
        acc[0][dt] = __builtin_amdgcn_mfma_f32_16x16x32_bf16(vf, pf[0], acc[0][dt], 0, 0, 0);
        acc[1][dt] = __builtin_amdgcn_mfma_f32_16x16x32_bf16(vf, pf[1], acc[1][dt], 0, 0, 0);
      }
      __builtin_amdgcn_s_setprio(0);
    }
    cur ^= 1;
  }

#pragma unroll
  for (int qt = 0; qt < 2; qt++) {
    lsum[qt] += __shfl_xor(lsum[qt], 16);
    lsum[qt] += __shfl_xor(lsum[qt], 32);
  }

  __syncthreads();
  const int gi = wv4 * 64 + lane;
  float* scr = (float*)sm + (size_t)gi * 36;
  if (g == 1) {
#pragma unroll
    for (int qt = 0; qt < 2; qt++)
#pragma unroll
      for (int dt = 0; dt < 4; dt++)
#pragma unroll
        for (int j = 0; j < 4; j++) scr[qt * 16 + dt * 4 + j] = acc[qt][dt][j];
    scr[32] = mold[0]; scr[33] = mold[1];
    scr[34] = lsum[0]; scr[35] = lsum[1];
  }
  __syncthreads();
  if (g == 0) {
#pragma unroll
    for (int qt = 0; qt < 2; qt++) {
      const float mB = scr[32 + qt], lB = scr[34 + qt];
      const float mN = fmaxf(mold[qt], mB);
      const float sA = exp2f(mold[qt] - mN);
      const float sB = exp2f(mB - mN);
      const float inv = 1.f / (lsum[qt] * sA + lB * sB);
      u16* ob = att + (size_t)(b * SS + q0 + wv4 * 32 + qt * 16 + la) * DM + h * DK + lg * 4;
#pragma unroll
      for (int dt = 0; dt < 4; dt++) {
        float o0 = (acc[qt][dt][0] * sA + scr[qt * 16 + dt * 4 + 0] * sB) * inv;
        float o1 = (acc[qt][dt][1] * sA + scr[qt * 16 + dt * 4 + 1] * sB) * inv;
        float o2 = (acc[qt][dt][2] * sA + scr[qt * 16 + dt * 4 + 2] * sB) * inv;
        float o3 = (acc[qt][dt][3] * sA + scr[qt * 16 + dt * 4 + 3] * sB) * inv;
        uint2 o;
        o.x = pk2bf(o0, o1);
        o.y = pk2bf(o2, o3);
        *(uint2*)(ob + dt * 16) = o;
      }
    }
  }
}

// ---------------------------------------------------------------------------
extern "C" void kernel_launch(void* const* d_in, const int* in_sizes, int n_in,
                              void* d_out, int out_size, void* d_ws, size_t ws_size,
                              hipStream_t stream) {
  const float* x    = (const float*)d_in[0];
  const float* wq   = (const float*)d_in[1];
  const float* bq   = (const float*)d_in[2];
  const float* wk   = (const float*)d_in[3];
  const float* bk   = (const float*)d_in[4];
  const float* wv   = (const float*)d_in[5];
  const float* bv   = (const float*)d_in[6];
  const float* wo   = (const float*)d_in[7];
  const float* bo   = (const float*)d_in[8];
  const float* w1   = (const float*)d_in[9];
  const float* b1   = (const float*)d_in[10];
  const float* w2   = (const float*)d_in[11];
  const float* b2   = (const float*)d_in[12];
  const float* ln1g = (const float*)d_in[13];
  const float* ln1b = (const float*)d_in[14];
  const float* ln2g = (const float*)d_in[15];
  const float* ln2b = (const float*)d_in[16];
  float* out = (float*)d_out;

  char* w = (char*)d_ws;
  const size_t MB = 1024ull * 1024ull;
  u16*   wqkv = (u16*)(w + 0 * MB);   // [3072][1024] bf16 (Q,K,V stacked)
  u16*   wot  = (u16*)(w + 6 * MB);   // [1024][1024]
  u16*   w1t  = (u16*)(w + 8 * MB);   // [4096][1024]
  u16*   w2t  = (u16*)(w + 16 * MB);  // [1024][4096]
  float* x2   = (float*)(w + 24 * MB);// [8192][1024] f32
  u16*   hb   = (u16*)(w + 56 * MB);  // [8192][1024] (h, then h2)
  u16*   qb   = (u16*)(w + 72 * MB);  // [8192][1024]; K at +8M u16, V^T at +16M u16
  u16*   kb   = (u16*)(w + 88 * MB);
  u16*   vtb  = (u16*)(w + 104 * MB); // [4][16][64][2048] V^T per head
  u16*   atb  = (u16*)(w + 120 * MB); // [8192][1024]
  u16*   ffb  = (u16*)(w + 72 * MB);  // [8192][4096] overlays q/k/vt/att

  // 1) ALL weight transposes in one launch (f32 -> bf16 W^T)
  k_transpose_all<<<dim3(12288), 256, 0, stream>>>(wq, wk, wv, wo, w1, w2,
                                                   wqkv, wot, w1t, w2t);

  // 2) LN1: x -> h (bf16)
  k_layernorm<<<MROWS / 4, 256, 0, stream>>>(x, ln1g, ln1b, hb);

  // 3) fused QKV projection: BM=256, BN=128 -> 24x32 = 768 blocks
  k_gemm_bt<4, 4><<<dim3(24, 32), 512, 0, stream>>>(hb, wqkv, bq, bk, bv, nullptr, qb,
                                                    MROWS, 3 * DM, DM);

  // 4) causal flash attention (swapped QK^T, split-KV, 8 waves)
  k_attn<<<dim3(1024), 512, 0, stream>>>(qb, kb, vtb, atb);

  // 5) O projection + residual (f32 x2): 8x32 = 256 blocks
  k_gemm_bt<1, 4><<<dim3(8, 32), 512, 0, stream>>>(atb, wot, bo, nullptr, nullptr, x, x2,
                                                   MROWS, DM, DM);

  // 6) LN2: x2 -> h2 (bf16, reuse hb)
  k_layernorm<<<MROWS / 4, 256, 0, stream>>>(x2, ln2g, ln2b, hb);

  // 7) FF1 + GELU: 256x256 template -> 16x32 = 512 blocks
  k_gemm256_gelu<<<dim3(16, 32), 512, 0, stream>>>(hb, w1t, b1, ffb,
                                                   MROWS, DFF, DM);

  // 8) FF2 + residual -> d_out (f32): 8x32 = 256 blocks
  k_gemm_bt<1, 4><<<dim3(8, 32), 512, 0, stream>>>(ffb, w2t, b2, nullptr, nullptr, x2, out,
                                                   MROWS, DM, DFF);
}